// Round 6
// baseline (379.947 us; speedup 1.0000x reference)
//
#include <hip/hip_runtime.h>
#include <hip/hip_bf16.h>
#include <stdint.h>

typedef unsigned short ushort;
typedef unsigned int uint;
typedef unsigned char uchar;

#define N_NODES 100000
#define N_EDGES 1600000
#define KDIM 192      // 3 * 64 concatenated h_j
#define HIDDEN 512
#define NCHUNK 782    // ceil(N/128)
#define NPART 782     // one partial per 128-node chunk
#define SDIM (KDIM*KDIM)
#define NPAIR 78      // 12*13/2 upper-triangle band pairs
#define PPB   9984    // uints per block partial: 78 frags * 128 uints
#define NSPLIT 8
#define LDT 194       // ushort stride of node-major LDS tile (192 + 2 pad)
#define NSLICE 256    // edge slices
#define EPS (N_EDGES/NSLICE)   // 6250 edges per slice

// ---- bucket sort params: bucket = dst>>8 (256 nodes per bucket) ----
#define NB 391        // ceil(100000/256)
#define BCAP 5120     // LDS record capacity per bucket (mean 4096, sd 64)

typedef __attribute__((ext_vector_type(8))) short short8;
typedef __attribute__((ext_vector_type(4))) short short4v;
typedef __attribute__((ext_vector_type(4))) uint uint4v;
typedef __attribute__((ext_vector_type(4))) float float4v;
typedef __attribute__((ext_vector_type(2))) float float2v;
typedef __attribute__((ext_vector_type(2))) uint uint2v;

__device__ __forceinline__ float bf2f(ushort u){
    uint x = ((uint)u) << 16;
    return __builtin_bit_cast(float, x);
}
__device__ __forceinline__ float bflo(uint u){
    return __builtin_bit_cast(float, u << 16);
}
__device__ __forceinline__ float bfhi(uint u){
    return __builtin_bit_cast(float, u & 0xffff0000u);
}
__device__ __forceinline__ ushort f2bf(float f){
    uint u = __builtin_bit_cast(uint, f);
    u += 0x7fffu + ((u >> 16) & 1u);   // round-to-nearest-even
    return (ushort)(u >> 16);
}

// ---- 1. per-slice bucket histogram (391 LDS counters) ----
__global__ __launch_bounds__(1024) void k_histA(const int* __restrict__ dst,
                                                uint* __restrict__ histA){
    __shared__ uint cnt[NB];
    int slice = blockIdx.x, t = threadIdx.x;
    for (int b = t; b < NB; b += 1024) cnt[b] = 0;
    __syncthreads();
    int e0 = slice * EPS;
    for (int i = t; i < EPS; i += 1024){
        uint d = (uint)dst[e0 + i];
        atomicAdd(&cnt[d >> 8], 1u);
    }
    __syncthreads();
    for (int b = t; b < NB; b += 1024) histA[(size_t)b*NSLICE + slice] = cnt[b];
}

// ---- 1b. per-bucket scan over slices -> slice bases + bucket totals ----
__global__ void k_scanSl(const uint* __restrict__ histA, uint* __restrict__ sbase,
                         uint* __restrict__ btot){
    __shared__ uint sc[NSLICE];
    int b = blockIdx.x, t = threadIdx.x;
    uint v = histA[(size_t)b*NSLICE + t];
    sc[t] = v; __syncthreads();
    for (int off = 1; off < 256; off <<= 1){
        uint u = (t >= off) ? sc[t - off] : 0;
        __syncthreads();
        sc[t] += u;
        __syncthreads();
    }
    sbase[(size_t)b*NSLICE + t] = sc[t] - v;
    if (t == 255) btot[b] = sc[255];
}

// ---- 1c. exclusive scan of bucket totals -> bucket starts ----
__global__ void k_scanBk(const uint* __restrict__ btot, uint* __restrict__ bstart){
    __shared__ uint sc[512];
    int t = threadIdx.x;
    uint v = (t < NB) ? btot[t] : 0;
    sc[t] = v; __syncthreads();
    for (int off = 1; off < 512; off <<= 1){
        uint u = (t >= off) ? sc[t - off] : 0;
        __syncthreads();
        sc[t] += u;
        __syncthreads();
    }
    if (t < NB) bstart[t] = sc[t] - v;
}

// ---- 2. pack records bucket-major; slot via LDS running offsets ----
__global__ __launch_bounds__(1024) void k_packA(const int* __restrict__ src,
                                                const int* __restrict__ dst,
                                                const uint* __restrict__ sbase,
                                                const uint* __restrict__ bstart,
                                                uint* __restrict__ rec){
    __shared__ uint arr[NB];
    int slice = blockIdx.x, t = threadIdx.x;
    for (int b = t; b < NB; b += 1024)
        arr[b] = bstart[b] + sbase[(size_t)b*NSLICE + slice];
    __syncthreads();
    int e0 = slice * EPS;
    for (int i = t; i < EPS; i += 1024){
        int e = e0 + i;
        uint d = (uint)dst[e];
        uint bk = d >> 8;
        uint slot = atomicAdd(&arr[bk], 1u);
        rec[slot] = (uint)src[e] | ((d & 255u) << 17);
    }
}

// ---- 3. per-bucket: count nodes in LDS, scan, emit deg/rowptr/nrm + csr ----
__global__ __launch_bounds__(256) void k_passB(const uint* __restrict__ rec,
                                               const uint* __restrict__ bstart,
                                               const uint* __restrict__ btot,
                                               int* __restrict__ csr,
                                               int* __restrict__ deg,
                                               int* __restrict__ rowptr,
                                               float* __restrict__ nrm){
    __shared__ uint recs[BCAP];
    __shared__ uint cntL[256];
    __shared__ uint ofs[256];
    int b = blockIdx.x, t = threadIdx.x;
    uint base = bstart[b], cnt = btot[b];
    cntL[t] = 0;
    __syncthreads();
    for (uint i = t; i < cnt; i += 256){
        uint rv = rec[base + i];
        if (i < BCAP) recs[i] = rv;
        atomicAdd(&cntL[(rv >> 17) & 255u], 1u);
    }
    __syncthreads();
    uint c = cntL[t];
    ofs[t] = c; __syncthreads();
    for (int off = 1; off < 256; off <<= 1){
        uint u = (t >= off) ? ofs[t - off] : 0;
        __syncthreads();
        ofs[t] += u;
        __syncthreads();
    }
    uint excl = ofs[t] - c;
    int node = b*256 + t;
    if (node < N_NODES){
        deg[node] = (int)c;
        rowptr[node] = (int)(base + excl);
        nrm[node] = rsqrtf((float)(c > 0 ? c : 1));
    }
    __syncthreads();
    ofs[t] = excl;
    __syncthreads();
    for (uint i = t; i < cnt; i += 256){
        uint rv = (i < BCAP) ? recs[i] : rec[base + i];
        uint n = (rv >> 17) & 255u;
        uint p = atomicAdd(&ofs[n], 1u);
        csr[base + p] = (int)(rv & 0x1FFFFu);
    }
}

// ---- 4. cast feats to bf16 pre-scaled by nrm ----
__global__ void k_cast(const float* __restrict__ feats, const float* __restrict__ nrm,
                       ushort* __restrict__ Hx){
    int i = blockIdx.x * 256 + threadIdx.x;   // float4 groups, 16 per node
    if (i < N_NODES * 16){
        float w = nrm[i >> 4];
        float4v v = ((const float4v*)feats)[i];
        short4v o;
        o[0] = (short)f2bf(v[0]*w); o[1] = (short)f2bf(v[1]*w);
        o[2] = (short)f2bf(v[2]*w); o[3] = (short)f2bf(v[3]*w);
        ((short4v*)Hx)[i] = o;
    }
}

// ---- 5. aggregation: 2 nodes per wave (half-wave each), dwordx4 gathers ----
template<bool WRITE_HS>
__global__ void k_agg(const ushort* __restrict__ inp,
                      ushort* __restrict__ H, int outoff,
                      ushort* __restrict__ Hs,
                      const int* __restrict__ rowptr, const int* __restrict__ deg,
                      const float* __restrict__ nrm, const int* __restrict__ csr){
    int node = (blockIdx.x << 3) + (threadIdx.x >> 5);
    int lane = threadIdx.x & 63;
    if (node >= N_NODES) return;
    int slot = (lane & 31) >> 3;   // 0..3
    int fb   = lane & 7;
    int beg = rowptr[node];
    int d   = deg[node];
    float acc[8] = {};
    int i = 0;
    for (; i + 8 <= d; i += 8){
        int sA = csr[beg + i + slot];
        int sB = csr[beg + i + 4 + slot];
        uint4v vA = *(const uint4v*)(inp + (long)sA*64 + fb*8);
        uint4v vB = *(const uint4v*)(inp + (long)sB*64 + fb*8);
        #pragma unroll
        for (int p = 0; p < 4; ++p){
            acc[2*p]   += bflo(vA[p]); acc[2*p+1] += bfhi(vA[p]);
            acc[2*p]   += bflo(vB[p]); acc[2*p+1] += bfhi(vB[p]);
        }
    }
    if (i + 4 <= d){
        int sA = csr[beg + i + slot];
        uint4v vA = *(const uint4v*)(inp + (long)sA*64 + fb*8);
        #pragma unroll
        for (int p = 0; p < 4; ++p){
            acc[2*p]   += bflo(vA[p]); acc[2*p+1] += bfhi(vA[p]);
        }
        i += 4;
    }
    if (i + slot < d){
        int s = csr[beg + i + slot];
        uint4v v = *(const uint4v*)(inp + (long)s*64 + fb*8);
        #pragma unroll
        for (int p = 0; p < 4; ++p){
            acc[2*p]   += bflo(v[p]); acc[2*p+1] += bfhi(v[p]);
        }
    }
    #pragma unroll
    for (int k = 0; k < 8; ++k){
        acc[k] += __shfl_xor(acc[k], 8);
        acc[k] += __shfl_xor(acc[k], 16);
    }
    if (slot == 0){
        float wn = nrm[node];
        short8 o;
        #pragma unroll
        for (int k = 0; k < 8; ++k) o[k] = (short)f2bf(wn * acc[k]);
        *(short8*)(H + (long)node*KDIM + outoff + fb*8) = o;
        if (WRITE_HS){
            float w2 = wn * wn;
            short8 o2;
            #pragma unroll
            for (int k = 0; k < 8; ++k) o2[k] = (short)f2bf(w2 * acc[k]);
            *(short8*)(Hs + (long)node*64 + fb*8) = o2;
        }
    }
}

// ---- 6. fold weights, split-K x8, 4 c per block ----
__global__ __launch_bounds__(192) void k_prepM1(const float* __restrict__ W0,
                                                const float* __restrict__ W1,
                                                const float* __restrict__ W2,
                                                const float* __restrict__ fcW,
                                                float* __restrict__ MTp){
    int ks = blockIdx.x;          // 0..7
    int c0 = blockIdx.y * 4;      // 0..508
    int jd = threadIdx.x;         // 0..191
    int j = jd >> 6, d = jd & 63;
    const float* W  = (j == 0) ? W0 : (j == 1) ? W1 : W2;
    const float* wp = W + (ks*64)*64 + d;
    const float* f0 = fcW + (long)(c0+0)*1536 + j*512 + ks*64;
    const float* f1 = fcW + (long)(c0+1)*1536 + j*512 + ks*64;
    const float* f2 = fcW + (long)(c0+2)*1536 + j*512 + ks*64;
    const float* f3 = fcW + (long)(c0+3)*1536 + j*512 + ks*64;
    float a0 = 0.f, a1 = 0.f, a2 = 0.f, a3 = 0.f;
    #pragma unroll 8
    for (int k = 0; k < 64; ++k){
        float w = wp[k*64];
        a0 += w * f0[k]; a1 += w * f1[k]; a2 += w * f2[k]; a3 += w * f3[k];
    }
    long base = (long)ks*(HIDDEN*KDIM) + (long)c0*KDIM + jd;
    MTp[base]         = a0;
    MTp[base + KDIM]  = a1;
    MTp[base + 2*KDIM]= a2;
    MTp[base + 3*KDIM]= a3;
}

// ---- 6a2. sum 8 partials, cast to bf16 ----
__global__ void k_prepM2(const float* __restrict__ MTp, ushort* __restrict__ MT){
    int i = blockIdx.x*256 + threadIdx.x;   // 0..98303
    if (i >= HIDDEN*KDIM) return;
    float s = 0.f;
    #pragma unroll
    for (int ks = 0; ks < 8; ++ks) s += MTp[(long)ks*(HIDDEN*KDIM) + i];
    MT[i] = f2bf(s);
}

// ---- 6b. folded bias: one block per channel, LDS reduce ----
__global__ __launch_bounds__(256) void k_bias(const float* __restrict__ b0,
                                              const float* __restrict__ b1,
                                              const float* __restrict__ b2,
                                              const float* __restrict__ fcW,
                                              const float* __restrict__ fcb,
                                              float* __restrict__ Bc){
    __shared__ float red[256];
    int c = blockIdx.x, t = threadIdx.x;
    const float* fw = fcW + (long)c*1536;
    float s = b0[t]*fw[t]          + b0[t+256]*fw[t+256]
            + b1[t]*fw[512+t]      + b1[t+256]*fw[512+t+256]
            + b2[t]*fw[1024+t]     + b2[t+256]*fw[1024+t+256];
    red[t] = s; __syncthreads();
    for (int off = 128; off > 0; off >>= 1){
        if (t < off) red[t] += red[t + off];
        __syncthreads();
    }
    if (t == 0) Bc[c] = fcb[c] + red[0];
}

// ---- 7. symmetric H^T H: node-major LDS, 78 upper-tri band pairs ----
// 2-wave blocks: wave w owns pairs with (p&1)==w (39 pairs, 156 acc VGPR).
template<int W>
__device__ __forceinline__ void do_pairs(const short8* frag, float4v* acc){
    int p = 0, c = 0;
    #pragma unroll
    for (int i = 0; i < 12; ++i)
        #pragma unroll
        for (int j = i; j < 12; ++j){
            if ((p & 1) == W){
                acc[c] = __builtin_amdgcn_mfma_f32_16x16x32_bf16(frag[i], frag[j], acc[c], 0,0,0);
                ++c;
            }
            ++p;
        }
}
template<int W>
__device__ __forceinline__ void store_pairs(const float4v* acc, uint* Pb, int lane){
    int p = 0, c = 0;
    #pragma unroll
    for (int i = 0; i < 12; ++i)
        #pragma unroll
        for (int j = i; j < 12; ++j){
            if ((p & 1) == W){
                uint2v v;
                v[0] = (uint)f2bf(acc[c][0]) | ((uint)f2bf(acc[c][1]) << 16);
                v[1] = (uint)f2bf(acc[c][2]) | ((uint)f2bf(acc[c][3]) << 16);
                *(uint2v*)(Pb + p*128 + lane*2) = v;
                ++c;
            }
            ++p;
        }
}

__global__ __launch_bounds__(128) void k_hth(const ushort* __restrict__ H,
                                             uint* __restrict__ P,
                                             float* __restrict__ msum){
    __shared__ ushort Ts[128*LDT];   // 49664 B, node-major
    int t = threadIdx.x;             // 0..127
    int w = t >> 6, lane = t & 63;
    int m16 = lane & 15, quad = lane >> 4;
    int n0 = blockIdx.x * 128;
    #pragma unroll
    for (int it = 0; it < 24; ++it){
        int flat = it*128 + t;           // 128 rows * 24 segs
        int row = flat / 24, seg = flat - row*24;
        int gr = n0 + row;
        short8 v = {0,0,0,0,0,0,0,0};
        if (gr < N_NODES) v = *(const short8*)(H + (long)gr*KDIM + seg*8);
        *(short8*)(Ts + row*LDT + seg*8) = v;
    }
    __syncthreads();
    float4v acc[39] = {};
    #pragma unroll
    for (int kt = 0; kt < 4; ++kt){
        short8 frag[12];
        #pragma unroll
        for (int b = 0; b < 12; ++b){
            short8 f;
            #pragma unroll
            for (int j = 0; j < 8; ++j)
                f[j] = (short)Ts[(kt*32 + quad*8 + j)*LDT + b*16 + m16];
            frag[b] = f;
        }
        if (w == 0) do_pairs<0>(frag, acc);
        else        do_pairs<1>(frag, acc);
    }
    // folded column sums (Ts untouched since staging)
    for (int c = t; c < KDIM; c += 128){
        float s = 0.f;
        #pragma unroll 4
        for (int n = 0; n < 128; ++n) s += bf2f(Ts[n*LDT + c]);
        atomicAdd(&msum[c], s);
    }
    uint* Pb = P + (long)blockIdx.x * PPB;
    if (w == 0) store_pairs<0>(acc, Pb, lane);
    else        store_pairs<1>(acc, Pb, lane);
}

// ---- 8. split-K reduce of partials (coalesced) ----
__global__ void k_reduce(const uint* __restrict__ P, float* __restrict__ SP){
    int p = blockIdx.x * 256 + threadIdx.x;   // 0..9983
    int y = blockIdx.y;
    int b0 = y * 98, b1 = min(b0 + 98, NPART);
    float lo = 0.f, hi = 0.f;
    for (int b = b0; b < b1; ++b){
        uint v = P[(long)b*PPB + p];
        lo += bf2f((ushort)(v & 0xffff));
        hi += bf2f((ushort)(v >> 16));
    }
    float2v o; o[0] = lo; o[1] = hi;
    *(float2v*)(SP + (long)y*(NPAIR*256) + p*2) = o;
}

// ---- 9. finalize covariance C (both triangles) from fragment layout ----
__global__ void k_finC(const float* __restrict__ SP, const float* __restrict__ msum,
                       float* __restrict__ C){
    int idx = blockIdx.x * 256 + threadIdx.x;   // 0..19967
    float s = 0.f;
    #pragma unroll
    for (int y = 0; y < NSPLIT; ++y) s += SP[(long)y*(NPAIR*256) + idx];
    int h = idx & 1, pu = idx >> 1;
    int p = pu >> 7, rem = pu & 127;
    int l = rem >> 1, u = rem & 1;
    int r = u*2 + h;
    int pi = 0, pj = 0, off = 0;
    #pragma unroll
    for (int k = 0; k < 12; ++k){
        int len = 12 - k;
        if (p >= off && p < off + len){ pi = k; pj = k + (p - off); }
        off += len;
    }
    int m = pi*16 + (l >> 4)*4 + r;
    int n = pj*16 + (l & 15);
    const float invN = 1.f / (float)N_NODES;
    float v = s*invN - (msum[m]*invN)*(msum[n]*invN);
    C[m*KDIM + n] = v;
    C[n*KDIM + m] = v;
}

// ---- 10. Vp[ks][c][d] = partial C @ M_c over K-slice ks (split-K x4, 4c/block) ----
__global__ __launch_bounds__(192) void k_cv1(const float* __restrict__ C,
                                             const ushort* __restrict__ MT,
                                             float* __restrict__ Vp){
    int ks = blockIdx.x;          // 0..3, 48-wide K slice
    int c0 = blockIdx.y * 4;      // 0..508
    int d  = threadIdx.x;         // 0..191
    const ushort* m0 = MT + (long)(c0+0)*KDIM + ks*48;
    const ushort* m1 = MT + (long)(c0+1)*KDIM + ks*48;
    const ushort* m2 = MT + (long)(c0+2)*KDIM + ks*48;
    const ushort* m3 = MT + (long)(c0+3)*KDIM + ks*48;
    const float* cp = C + (long)(ks*48)*KDIM + d;
    float a0 = 0.f, a1 = 0.f, a2 = 0.f, a3 = 0.f;
    #pragma unroll 8
    for (int k = 0; k < 48; ++k){
        float cv = cp[(long)k*KDIM];
        a0 += bf2f(m0[k]) * cv; a1 += bf2f(m1[k]) * cv;
        a2 += bf2f(m2[k]) * cv; a3 += bf2f(m3[k]) * cv;
    }
    long base = (long)ks*(HIDDEN*KDIM) + (long)c0*KDIM + d;
    Vp[base]          = a0;
    Vp[base + KDIM]   = a1;
    Vp[base + 2*KDIM] = a2;
    Vp[base + 3*KDIM] = a3;
}

// ---- 11a. BN solve per channel: rr[c], tmpBN[c] (512 blocks, LDS reduce) ----
__global__ __launch_bounds__(192) void k_solveA(const float* __restrict__ Vp,
                                                const ushort* __restrict__ MT,
                                                const float* __restrict__ msum,
                                                const float* __restrict__ Bc,
                                                const float* __restrict__ gamma,
                                                const float* __restrict__ beta,
                                                float* __restrict__ rr,
                                                float* __restrict__ tmpBN){
    __shared__ float redM[192];
    __shared__ float redV[192];
    int c = blockIdx.x, d = threadIdx.x;
    const float invN = 1.f / (float)N_NODES;
    float m = bf2f(MT[(long)c*KDIM + d]);
    long vi = (long)c*KDIM + d;
    float vsum = Vp[vi] + Vp[vi + HIDDEN*KDIM] + Vp[vi + 2*HIDDEN*KDIM]
               + Vp[vi + 3*HIDDEN*KDIM];
    redM[d] = msum[d]*invN * m;
    redV[d] = vsum * m;
    __syncthreads();
    for (int off = 96; off >= 3; off >>= 1){
        if (d < off){ redM[d] += redM[d + off]; redV[d] += redV[d + off]; }
        __syncthreads();
    }
    if (d == 0){
        float mu  = Bc[c] + redM[0] + redM[1] + redM[2];
        float var = redV[0] + redV[1] + redV[2];
        float r = gamma[c] * rsqrtf(var + 1e-5f);
        rr[c] = r;
        tmpBN[c] = r * (Bc[c] - mu) + beta[c];
    }
}

// ---- 11b. cvec[o] = sum_k q_k tmpBN[k*64+o] ----
__global__ void k_solveB(const float* __restrict__ tmpBN, const float* __restrict__ q,
                         float* __restrict__ cvec){
    int c = threadIdx.x;   // 0..63
    float s = 0.f;
    #pragma unroll
    for (int k = 0; k < 8; ++k) s += q[k] * tmpBN[k*64 + c];
    cvec[c] = s;
}

// ---- 12. fold rho into M: GT[o][d] = sum_k q_k r_{k64+o} MT[k64+o][d] ----
__global__ void k_buildG(const ushort* __restrict__ MT, const float* __restrict__ rr,
                         const float* __restrict__ q, ushort* __restrict__ GT){
    int o = blockIdx.x, d = threadIdx.x;  // 64 x 192
    float s = 0.f;
    #pragma unroll
    for (int k = 0; k < 8; ++k)
        s += q[k] * rr[k*64 + o] * bf2f(MT[(k*64 + o)*KDIM + d]);
    GT[o*KDIM + d] = f2bf(s);
}

// ---- 13. out = H @ GT^T + cvec ----
#define LDA 200
__global__ __launch_bounds__(256) void k_outgemm(const ushort* __restrict__ H,
                                                 const ushort* __restrict__ GT,
                                                 const float* __restrict__ cvec,
                                                 float* __restrict__ out){
    __shared__ ushort As[128*LDA];
    __shared__ ushort Gs[64*LDA];
    int t = threadIdx.x;
    int n0 = blockIdx.x * 128;
    int w = t >> 6, lane = t & 63;
    int m16 = lane & 15, quad = lane >> 4;
    int wr = w * 32;
    float4v acc[2][4] = {};
    #pragma unroll
    for (int it = 0; it < 12; ++it){
        int flat = it*256 + t;               // 128 rows * 24 segs
        int row = flat / 24, seg = flat - row*24;
        int gr = n0 + row;
        short8 v = {0,0,0,0,0,0,0,0};
        if (gr < N_NODES) v = *(const short8*)(H + (long)gr*KDIM + seg*8);
        *(short8*)(As + row*LDA + seg*8) = v;
    }
    #pragma unroll
    for (int it = 0; it < 6; ++it){
        int flat = it*256 + t;               // 64 rows * 24 segs
        int row = flat / 24, seg = flat - row*24;
        short8 v = *(const short8*)(GT + row*KDIM + seg*8);
        *(short8*)(Gs + row*LDA + seg*8) = v;
    }
    __syncthreads();
    #pragma unroll
    for (int kk = 0; kk < 192; kk += 32){
        short8 af[2], bf[4];
        #pragma unroll
        for (int i = 0; i < 2; ++i)
            af[i] = *(const short8*)(As + (wr + i*16 + m16)*LDA + kk + quad*8);
        #pragma unroll
        for (int j = 0; j < 4; ++j)
            bf[j] = *(const short8*)(Gs + (j*16 + m16)*LDA + kk + quad*8);
        #pragma unroll
        for (int i = 0; i < 2; ++i)
            #pragma unroll
            for (int j = 0; j < 4; ++j)
                acc[i][j] = __builtin_amdgcn_mfma_f32_16x16x32_bf16(af[i], bf[j], acc[i][j], 0,0,0);
    }
    #pragma unroll
    for (int i = 0; i < 2; ++i)
        #pragma unroll
        for (int j = 0; j < 4; ++j)
            #pragma unroll
            for (int r = 0; r < 4; ++r){
                int rowg = n0 + wr + i*16 + quad*4 + r;
                int o = j*16 + m16;
                if (rowg < N_NODES) out[(long)rowg*64 + o] = acc[i][j][r] + cvec[o];
            }
}

extern "C" void kernel_launch(void* const* d_in, const int* in_sizes, int n_in,
                              void* d_out, int out_size, void* d_ws, size_t ws_size,
                              hipStream_t stream) {
    const float* feats = (const float*)d_in[0];
    const int*   src   = (const int*)  d_in[1];
    const int*   dst   = (const int*)  d_in[2];
    const float* W0    = (const float*)d_in[3];
    const float* b0    = (const float*)d_in[4];
    const float* W1    = (const float*)d_in[5];
    const float* b1    = (const float*)d_in[6];
    const float* W2    = (const float*)d_in[7];
    const float* b2    = (const float*)d_in[8];
    const float* fcW   = (const float*)d_in[9];
    const float* fcb   = (const float*)d_in[10];
    const float* gamma = (const float*)d_in[11];
    const float* beta  = (const float*)d_in[12];
    const float* q     = (const float*)d_in[13];
    float* out = (float*)d_out;

    char* ws = (char*)d_ws;
    size_t off = 0;
    auto alloc = [&](size_t bytes) -> char* {
        char* p = ws + off;
        off = (off + bytes + 511) & ~(size_t)511;
        return p;
    };
    uint*   histA   = (uint*)  alloc((size_t)NB * NSLICE * 4);
    uint*   sbase   = (uint*)  alloc((size_t)NB * NSLICE * 4);
    uint*   btot    = (uint*)  alloc((size_t)NB * 4);
    uint*   bstart  = (uint*)  alloc((size_t)NB * 4);
    uint*   rec     = (uint*)  alloc((size_t)N_EDGES * 4);
    int*    deg     = (int*)   alloc((size_t)N_NODES * 4);
    int*    rowptr  = (int*)   alloc((size_t)N_NODES * 4);
    float*  nrm     = (float*) alloc((size_t)N_NODES * 4);
    int*    csr     = (int*)   alloc((size_t)N_EDGES * 4);
    ushort* Hx      = (ushort*)alloc((size_t)N_NODES * 64 * 2);
    ushort* HsB     = (ushort*)alloc((size_t)N_NODES * 64 * 2);
    ushort* H       = (ushort*)alloc((size_t)N_NODES * KDIM * 2);
    ushort* MT      = (ushort*)alloc((size_t)HIDDEN * KDIM * 2);
    float*  MTp     = (float*) alloc((size_t)8 * HIDDEN * KDIM * 4);
    float*  Bc      = (float*) alloc((size_t)HIDDEN * 4);
    float*  msum    = (float*) alloc((size_t)KDIM * 4);
    uint*   P       = (uint*)  alloc((size_t)NPART * PPB * 4);
    float*  SP      = (float*) alloc((size_t)NSPLIT * NPAIR * 256 * 4);
    float*  C       = (float*) alloc((size_t)SDIM * 4);
    float*  Vp      = (float*) alloc((size_t)4 * HIDDEN * KDIM * 4);
    float*  rr      = (float*) alloc((size_t)HIDDEN * 4);
    float*  tmpBN   = (float*) alloc((size_t)HIDDEN * 4);
    float*  cvec    = (float*) alloc((size_t)64 * 4);
    ushort* GT      = (ushort*)alloc((size_t)64 * KDIM * 2);
    (void)ws_size; (void)n_in; (void)in_sizes; (void)out_size;

    hipMemsetAsync(msum, 0, (size_t)KDIM * 4, stream);

    k_histA <<<NSLICE, 1024, 0, stream>>>(dst, histA);
    k_scanSl<<<NB, 256, 0, stream>>>(histA, sbase, btot);
    k_scanBk<<<1, 512, 0, stream>>>(btot, bstart);
    k_packA <<<NSLICE, 1024, 0, stream>>>(src, dst, sbase, bstart, rec);
    k_passB <<<NB, 256, 0, stream>>>(rec, bstart, btot, csr, deg, rowptr, nrm);

    k_cast  <<<(N_NODES*16 + 255)/256, 256, 0, stream>>>(feats, nrm, Hx);

    int aggGrid = (N_NODES + 7) / 8;
    k_agg<true> <<<aggGrid, 256, 0, stream>>>(Hx,  H, 0,   HsB, rowptr, deg, nrm, csr);
    k_agg<true> <<<aggGrid, 256, 0, stream>>>(HsB, H, 64,  Hx,  rowptr, deg, nrm, csr);
    k_agg<false><<<aggGrid, 256, 0, stream>>>(Hx,  H, 128, HsB, rowptr, deg, nrm, csr);

    dim3 pmGrid(8, HIDDEN/4);
    k_prepM1<<<pmGrid, 192, 0, stream>>>(W0, W1, W2, fcW, MTp);
    k_prepM2<<<(HIDDEN*KDIM + 255)/256, 256, 0, stream>>>(MTp, MT);
    k_bias <<<HIDDEN, 256, 0, stream>>>(b0, b1, b2, fcW, fcb, Bc);

    k_hth   <<<NCHUNK, 128, 0, stream>>>(H, P, msum);
    dim3 rGrid(PPB/256, NSPLIT);
    k_reduce<<<rGrid, 256, 0, stream>>>(P, SP);
    k_finC  <<<NPAIR, 256, 0, stream>>>(SP, msum, C);
    dim3 cvGrid(4, HIDDEN/4);
    k_cv1   <<<cvGrid, 192, 0, stream>>>(C, MT, Vp);
    k_solveA<<<HIDDEN, 192, 0, stream>>>(Vp, MT, msum, Bc, gamma, beta, rr, tmpBN);
    k_solveB<<<1, 64, 0, stream>>>(tmpBN, q, cvec);
    k_buildG<<<64, KDIM, 0, stream>>>(MT, rr, q, GT);

    k_outgemm<<<NCHUNK, 256, 0, stream>>>(H, GT, cvec, out);
}

// Round 7
// 362.119 us; speedup vs baseline: 1.0492x; 1.0492x over previous
//
#include <hip/hip_runtime.h>
#include <hip/hip_bf16.h>
#include <stdint.h>

typedef unsigned short ushort;
typedef unsigned int uint;
typedef unsigned char uchar;

#define N_NODES 100000
#define N_EDGES 1600000
#define KDIM 192      // 3 * 64 concatenated h_j
#define HIDDEN 512
#define NCHUNK 782    // ceil(N/128)
#define NCH 2         // chunks accumulated per k_hth block
#define NPART 391     // NCHUNK/NCH partial blocks
#define SDIM (KDIM*KDIM)
#define NPAIR 78      // 12*13/2 upper-triangle band pairs
#define PPB   9984    // uints per block partial: 78 frags * 128 uints
#define NSPLIT 8
#define LDT 194       // ushort stride of node-major LDS tile (192 + 2 pad)
#define NSLICE 256    // edge slices
#define EPS (N_EDGES/NSLICE)   // 6250 edges per slice

// ---- bucket sort params: bucket = dst>>8 (256 nodes per bucket) ----
#define NB 391        // ceil(100000/256)
#define BCAP 5120     // LDS record capacity per bucket (mean 4096, sd 64)

typedef __attribute__((ext_vector_type(8))) short short8;
typedef __attribute__((ext_vector_type(4))) short short4v;
typedef __attribute__((ext_vector_type(4))) uint uint4v;
typedef __attribute__((ext_vector_type(4))) float float4v;
typedef __attribute__((ext_vector_type(2))) float float2v;
typedef __attribute__((ext_vector_type(2))) uint uint2v;

__device__ __forceinline__ float bf2f(ushort u){
    uint x = ((uint)u) << 16;
    return __builtin_bit_cast(float, x);
}
__device__ __forceinline__ float bflo(uint u){
    return __builtin_bit_cast(float, u << 16);
}
__device__ __forceinline__ float bfhi(uint u){
    return __builtin_bit_cast(float, u & 0xffff0000u);
}
__device__ __forceinline__ ushort f2bf(float f){
    uint u = __builtin_bit_cast(uint, f);
    u += 0x7fffu + ((u >> 16) & 1u);   // round-to-nearest-even
    return (ushort)(u >> 16);
}

// ---- 1. per-slice bucket histogram (391 LDS counters) ----
__global__ __launch_bounds__(1024) void k_histA(const int* __restrict__ dst,
                                                uint* __restrict__ histA){
    __shared__ uint cnt[NB];
    int slice = blockIdx.x, t = threadIdx.x;
    for (int b = t; b < NB; b += 1024) cnt[b] = 0;
    __syncthreads();
    int e0 = slice * EPS;
    for (int i = t; i < EPS; i += 1024){
        uint d = (uint)dst[e0 + i];
        atomicAdd(&cnt[d >> 8], 1u);
    }
    __syncthreads();
    for (int b = t; b < NB; b += 1024) histA[(size_t)b*NSLICE + slice] = cnt[b];
}

// ---- 1b. per-bucket scan over slices -> slice bases + bucket totals ----
__global__ void k_scanSl(const uint* __restrict__ histA, uint* __restrict__ sbase,
                         uint* __restrict__ btot){
    __shared__ uint sc[NSLICE];
    int b = blockIdx.x, t = threadIdx.x;
    uint v = histA[(size_t)b*NSLICE + t];
    sc[t] = v; __syncthreads();
    for (int off = 1; off < 256; off <<= 1){
        uint u = (t >= off) ? sc[t - off] : 0;
        __syncthreads();
        sc[t] += u;
        __syncthreads();
    }
    sbase[(size_t)b*NSLICE + t] = sc[t] - v;
    if (t == 255) btot[b] = sc[255];
}

// ---- 1c. exclusive scan of bucket totals -> bucket starts ----
__global__ void k_scanBk(const uint* __restrict__ btot, uint* __restrict__ bstart){
    __shared__ uint sc[512];
    int t = threadIdx.x;
    uint v = (t < NB) ? btot[t] : 0;
    sc[t] = v; __syncthreads();
    for (int off = 1; off < 512; off <<= 1){
        uint u = (t >= off) ? sc[t - off] : 0;
        __syncthreads();
        sc[t] += u;
        __syncthreads();
    }
    if (t < NB) bstart[t] = sc[t] - v;
}

// ---- 2. pack records bucket-major; slot via LDS running offsets ----
__global__ __launch_bounds__(1024) void k_packA(const int* __restrict__ src,
                                                const int* __restrict__ dst,
                                                const uint* __restrict__ sbase,
                                                const uint* __restrict__ bstart,
                                                uint* __restrict__ rec){
    __shared__ uint arr[NB];
    int slice = blockIdx.x, t = threadIdx.x;
    for (int b = t; b < NB; b += 1024)
        arr[b] = bstart[b] + sbase[(size_t)b*NSLICE + slice];
    __syncthreads();
    int e0 = slice * EPS;
    for (int i = t; i < EPS; i += 1024){
        int e = e0 + i;
        uint d = (uint)dst[e];
        uint bk = d >> 8;
        uint slot = atomicAdd(&arr[bk], 1u);
        rec[slot] = (uint)src[e] | ((d & 255u) << 17);
    }
}

// ---- 3. per-bucket: count nodes in LDS, scan, emit deg/rowptr/nrm + csr ----
__global__ __launch_bounds__(256) void k_passB(const uint* __restrict__ rec,
                                               const uint* __restrict__ bstart,
                                               const uint* __restrict__ btot,
                                               int* __restrict__ csr,
                                               int* __restrict__ deg,
                                               int* __restrict__ rowptr,
                                               float* __restrict__ nrm){
    __shared__ uint recs[BCAP];
    __shared__ uint cntL[256];
    __shared__ uint ofs[256];
    int b = blockIdx.x, t = threadIdx.x;
    uint base = bstart[b], cnt = btot[b];
    cntL[t] = 0;
    __syncthreads();
    for (uint i = t; i < cnt; i += 256){
        uint rv = rec[base + i];
        if (i < BCAP) recs[i] = rv;
        atomicAdd(&cntL[(rv >> 17) & 255u], 1u);
    }
    __syncthreads();
    uint c = cntL[t];
    ofs[t] = c; __syncthreads();
    for (int off = 1; off < 256; off <<= 1){
        uint u = (t >= off) ? ofs[t - off] : 0;
        __syncthreads();
        ofs[t] += u;
        __syncthreads();
    }
    uint excl = ofs[t] - c;
    int node = b*256 + t;
    if (node < N_NODES){
        deg[node] = (int)c;
        rowptr[node] = (int)(base + excl);
        nrm[node] = rsqrtf((float)(c > 0 ? c : 1));
    }
    __syncthreads();
    ofs[t] = excl;
    __syncthreads();
    for (uint i = t; i < cnt; i += 256){
        uint rv = (i < BCAP) ? recs[i] : rec[base + i];
        uint n = (rv >> 17) & 255u;
        uint p = atomicAdd(&ofs[n], 1u);
        csr[base + p] = (int)(rv & 0x1FFFFu);
    }
}

// ---- 4. cast feats to bf16 pre-scaled by nrm ----
__global__ void k_cast(const float* __restrict__ feats, const float* __restrict__ nrm,
                       ushort* __restrict__ Hx){
    int i = blockIdx.x * 256 + threadIdx.x;   // float4 groups, 16 per node
    if (i < N_NODES * 16){
        float w = nrm[i >> 4];
        float4v v = ((const float4v*)feats)[i];
        short4v o;
        o[0] = (short)f2bf(v[0]*w); o[1] = (short)f2bf(v[1]*w);
        o[2] = (short)f2bf(v[2]*w); o[3] = (short)f2bf(v[3]*w);
        ((short4v*)Hx)[i] = o;
    }
}

// ---- 5. aggregation: 2 nodes per wave; deg<=32 fast path issues all gathers
//      up-front (static v[8], per-lane accumulation order identical to loop) ----
template<bool WRITE_HS>
__global__ void k_agg(const ushort* __restrict__ inp,
                      ushort* __restrict__ H, int outoff,
                      ushort* __restrict__ Hs,
                      const int* __restrict__ rowptr, const int* __restrict__ deg,
                      const float* __restrict__ nrm, const int* __restrict__ csr){
    int node = (blockIdx.x << 3) + (threadIdx.x >> 5);
    int lane = threadIdx.x & 63;
    if (node >= N_NODES) return;
    int slot = (lane & 31) >> 3;   // 0..3
    int fb   = lane & 7;
    int beg = rowptr[node];
    int d   = deg[node];
    float acc[8] = {};
    if (d <= 32){
        uint4v v[8];
        #pragma unroll
        for (int k = 0; k < 8; ++k){
            if (k*4 < d){                         // uniform per node
                int i = slot + k*4;
                int e = beg + (i < d ? i : d-1);  // clamp (d>=1 here)
                int s = csr[e];
                v[k] = *(const uint4v*)(inp + (long)s*64 + fb*8);
            }
        }
        #pragma unroll
        for (int k = 0; k < 8; ++k){
            if (slot + k*4 < d){
                #pragma unroll
                for (int p = 0; p < 4; ++p){
                    acc[2*p]   += bflo(v[k][p]);
                    acc[2*p+1] += bfhi(v[k][p]);
                }
            }
        }
    } else {
        int i = 0;
        for (; i + 8 <= d; i += 8){
            int sA = csr[beg + i + slot];
            int sB = csr[beg + i + 4 + slot];
            uint4v vA = *(const uint4v*)(inp + (long)sA*64 + fb*8);
            uint4v vB = *(const uint4v*)(inp + (long)sB*64 + fb*8);
            #pragma unroll
            for (int p = 0; p < 4; ++p){
                acc[2*p]   += bflo(vA[p]); acc[2*p+1] += bfhi(vA[p]);
                acc[2*p]   += bflo(vB[p]); acc[2*p+1] += bfhi(vB[p]);
            }
        }
        if (i + 4 <= d){
            int sA = csr[beg + i + slot];
            uint4v vA = *(const uint4v*)(inp + (long)sA*64 + fb*8);
            #pragma unroll
            for (int p = 0; p < 4; ++p){
                acc[2*p]   += bflo(vA[p]); acc[2*p+1] += bfhi(vA[p]);
            }
            i += 4;
        }
        if (i + slot < d){
            int s = csr[beg + i + slot];
            uint4v v = *(const uint4v*)(inp + (long)s*64 + fb*8);
            #pragma unroll
            for (int p = 0; p < 4; ++p){
                acc[2*p]   += bflo(v[p]); acc[2*p+1] += bfhi(v[p]);
            }
        }
    }
    #pragma unroll
    for (int k = 0; k < 8; ++k){
        acc[k] += __shfl_xor(acc[k], 8);
        acc[k] += __shfl_xor(acc[k], 16);
    }
    if (slot == 0){
        float wn = nrm[node];
        short8 o;
        #pragma unroll
        for (int k = 0; k < 8; ++k) o[k] = (short)f2bf(wn * acc[k]);
        *(short8*)(H + (long)node*KDIM + outoff + fb*8) = o;
        if (WRITE_HS){
            float w2 = wn * wn;
            short8 o2;
            #pragma unroll
            for (int k = 0; k < 8; ++k) o2[k] = (short)f2bf(w2 * acc[k]);
            *(short8*)(Hs + (long)node*64 + fb*8) = o2;
        }
    }
}

// ---- 6. fold weights, split-K x8, 4 c per block ----
__global__ __launch_bounds__(192) void k_prepM1(const float* __restrict__ W0,
                                                const float* __restrict__ W1,
                                                const float* __restrict__ W2,
                                                const float* __restrict__ fcW,
                                                float* __restrict__ MTp){
    int ks = blockIdx.x;          // 0..7
    int c0 = blockIdx.y * 4;      // 0..508
    int jd = threadIdx.x;         // 0..191
    int j = jd >> 6, d = jd & 63;
    const float* W  = (j == 0) ? W0 : (j == 1) ? W1 : W2;
    const float* wp = W + (ks*64)*64 + d;
    const float* f0 = fcW + (long)(c0+0)*1536 + j*512 + ks*64;
    const float* f1 = fcW + (long)(c0+1)*1536 + j*512 + ks*64;
    const float* f2 = fcW + (long)(c0+2)*1536 + j*512 + ks*64;
    const float* f3 = fcW + (long)(c0+3)*1536 + j*512 + ks*64;
    float a0 = 0.f, a1 = 0.f, a2 = 0.f, a3 = 0.f;
    #pragma unroll 8
    for (int k = 0; k < 64; ++k){
        float w = wp[k*64];
        a0 += w * f0[k]; a1 += w * f1[k]; a2 += w * f2[k]; a3 += w * f3[k];
    }
    long base = (long)ks*(HIDDEN*KDIM) + (long)c0*KDIM + jd;
    MTp[base]         = a0;
    MTp[base + KDIM]  = a1;
    MTp[base + 2*KDIM]= a2;
    MTp[base + 3*KDIM]= a3;
}

// ---- 6a2. sum 8 partials, cast to bf16 ----
__global__ void k_prepM2(const float* __restrict__ MTp, ushort* __restrict__ MT){
    int i = blockIdx.x*256 + threadIdx.x;   // 0..98303
    if (i >= HIDDEN*KDIM) return;
    float s = 0.f;
    #pragma unroll
    for (int ks = 0; ks < 8; ++ks) s += MTp[(long)ks*(HIDDEN*KDIM) + i];
    MT[i] = f2bf(s);
}

// ---- 6b. folded bias: one block per channel, LDS reduce ----
__global__ __launch_bounds__(256) void k_bias(const float* __restrict__ b0,
                                              const float* __restrict__ b1,
                                              const float* __restrict__ b2,
                                              const float* __restrict__ fcW,
                                              const float* __restrict__ fcb,
                                              float* __restrict__ Bc){
    __shared__ float red[256];
    int c = blockIdx.x, t = threadIdx.x;
    const float* fw = fcW + (long)c*1536;
    float s = b0[t]*fw[t]          + b0[t+256]*fw[t+256]
            + b1[t]*fw[512+t]      + b1[t+256]*fw[512+t+256]
            + b2[t]*fw[1024+t]     + b2[t+256]*fw[1024+t+256];
    red[t] = s; __syncthreads();
    for (int off = 128; off > 0; off >>= 1){
        if (t < off) red[t] += red[t + off];
        __syncthreads();
    }
    if (t == 0) Bc[c] = fcb[c] + red[0];
}

// ---- 7. symmetric H^T H: node-major LDS, 78 upper-tri band pairs ----
// 4-wave blocks, (p&3)==w (20 acc max, VGPR ~128), NCH=2 chunks per block.
template<int W>
__device__ __forceinline__ void do_pairs(const short8* frag, float4v* acc){
    int p = 0, c = 0;
    #pragma unroll
    for (int i = 0; i < 12; ++i)
        #pragma unroll
        for (int j = i; j < 12; ++j){
            if ((p & 3) == W){
                acc[c] = __builtin_amdgcn_mfma_f32_16x16x32_bf16(frag[i], frag[j], acc[c], 0,0,0);
                ++c;
            }
            ++p;
        }
}
template<int W>
__device__ __forceinline__ void store_pairs(const float4v* acc, uint* Pb, int lane){
    int p = 0, c = 0;
    #pragma unroll
    for (int i = 0; i < 12; ++i)
        #pragma unroll
        for (int j = i; j < 12; ++j){
            if ((p & 3) == W){
                uint2v v;
                v[0] = (uint)f2bf(acc[c][0]) | ((uint)f2bf(acc[c][1]) << 16);
                v[1] = (uint)f2bf(acc[c][2]) | ((uint)f2bf(acc[c][3]) << 16);
                *(uint2v*)(Pb + p*128 + lane*2) = v;
                ++c;
            }
            ++p;
        }
}

__global__ __launch_bounds__(256, 2) void k_hth(const ushort* __restrict__ H,
                                                uint* __restrict__ P,
                                                float* __restrict__ msum){
    __shared__ ushort Ts[128*LDT];   // 49664 B, node-major
    int t = threadIdx.x;
    int w = t >> 6, lane = t & 63;
    int m16 = lane & 15, quad = lane >> 4;
    float4v acc[20] = {};
    #pragma unroll
    for (int cc = 0; cc < NCH; ++cc){
        int chunk = blockIdx.x * NCH + cc;
        int n0 = chunk * 128;
        #pragma unroll
        for (int it = 0; it < 12; ++it){
            int flat = it*256 + t;           // 128 rows * 24 segs
            int row = flat / 24, seg = flat - row*24;
            int gr = n0 + row;
            short8 v = {0,0,0,0,0,0,0,0};
            if (gr < N_NODES) v = *(const short8*)(H + (long)gr*KDIM + seg*8);
            *(short8*)(Ts + row*LDT + seg*8) = v;
        }
        __syncthreads();
        #pragma unroll
        for (int kt = 0; kt < 4; ++kt){
            short8 frag[12];
            #pragma unroll
            for (int b = 0; b < 12; ++b){
                short8 f;
                #pragma unroll
                for (int j = 0; j < 8; ++j)
                    f[j] = (short)Ts[(kt*32 + quad*8 + j)*LDT + b*16 + m16];
                frag[b] = f;
            }
            if      (w == 0) do_pairs<0>(frag, acc);
            else if (w == 1) do_pairs<1>(frag, acc);
            else if (w == 2) do_pairs<2>(frag, acc);
            else             do_pairs<3>(frag, acc);
        }
        // folded column sums (Ts untouched since staging)
        if (t < KDIM){
            float s = 0.f;
            #pragma unroll 4
            for (int n = 0; n < 128; ++n) s += bf2f(Ts[n*LDT + t]);
            atomicAdd(&msum[t], s);
        }
        __syncthreads();
    }
    uint* Pb = P + (long)blockIdx.x * PPB;
    if      (w == 0) store_pairs<0>(acc, Pb, lane);
    else if (w == 1) store_pairs<1>(acc, Pb, lane);
    else if (w == 2) store_pairs<2>(acc, Pb, lane);
    else             store_pairs<3>(acc, Pb, lane);
}

// ---- 8. split-K reduce of partials (coalesced) ----
__global__ void k_reduce(const uint* __restrict__ P, float* __restrict__ SP){
    int p = blockIdx.x * 256 + threadIdx.x;   // 0..9983
    int y = blockIdx.y;
    int b0 = y * 49, b1 = min(b0 + 49, NPART);
    float lo = 0.f, hi = 0.f;
    for (int b = b0; b < b1; ++b){
        uint v = P[(long)b*PPB + p];
        lo += bf2f((ushort)(v & 0xffff));
        hi += bf2f((ushort)(v >> 16));
    }
    float2v o; o[0] = lo; o[1] = hi;
    *(float2v*)(SP + (long)y*(NPAIR*256) + p*2) = o;
}

// ---- 9. finalize covariance C (both triangles) from fragment layout ----
__global__ void k_finC(const float* __restrict__ SP, const float* __restrict__ msum,
                       float* __restrict__ C){
    int idx = blockIdx.x * 256 + threadIdx.x;   // 0..19967
    float s = 0.f;
    #pragma unroll
    for (int y = 0; y < NSPLIT; ++y) s += SP[(long)y*(NPAIR*256) + idx];
    int h = idx & 1, pu = idx >> 1;
    int p = pu >> 7, rem = pu & 127;
    int l = rem >> 1, u = rem & 1;
    int r = u*2 + h;
    int pi = 0, pj = 0, off = 0;
    #pragma unroll
    for (int k = 0; k < 12; ++k){
        int len = 12 - k;
        if (p >= off && p < off + len){ pi = k; pj = k + (p - off); }
        off += len;
    }
    int m = pi*16 + (l >> 4)*4 + r;
    int n = pj*16 + (l & 15);
    const float invN = 1.f / (float)N_NODES;
    float v = s*invN - (msum[m]*invN)*(msum[n]*invN);
    C[m*KDIM + n] = v;
    C[n*KDIM + m] = v;
}

// ---- 10. Vp[ks][c][d] = partial C @ M_c over K-slice ks (split-K x4, 4c/block) ----
__global__ __launch_bounds__(192) void k_cv1(const float* __restrict__ C,
                                             const ushort* __restrict__ MT,
                                             float* __restrict__ Vp){
    int ks = blockIdx.x;          // 0..3, 48-wide K slice
    int c0 = blockIdx.y * 4;      // 0..508
    int d  = threadIdx.x;         // 0..191
    const ushort* m0 = MT + (long)(c0+0)*KDIM + ks*48;
    const ushort* m1 = MT + (long)(c0+1)*KDIM + ks*48;
    const ushort* m2 = MT + (long)(c0+2)*KDIM + ks*48;
    const ushort* m3 = MT + (long)(c0+3)*KDIM + ks*48;
    const float* cp = C + (long)(ks*48)*KDIM + d;
    float a0 = 0.f, a1 = 0.f, a2 = 0.f, a3 = 0.f;
    #pragma unroll 8
    for (int k = 0; k < 48; ++k){
        float cv = cp[(long)k*KDIM];
        a0 += bf2f(m0[k]) * cv; a1 += bf2f(m1[k]) * cv;
        a2 += bf2f(m2[k]) * cv; a3 += bf2f(m3[k]) * cv;
    }
    long base = (long)ks*(HIDDEN*KDIM) + (long)c0*KDIM + d;
    Vp[base]          = a0;
    Vp[base + KDIM]   = a1;
    Vp[base + 2*KDIM] = a2;
    Vp[base + 3*KDIM] = a3;
}

// ---- 11a. BN solve per channel: rr[c], tmpBN[c] (512 blocks, LDS reduce) ----
__global__ __launch_bounds__(192) void k_solveA(const float* __restrict__ Vp,
                                                const ushort* __restrict__ MT,
                                                const float* __restrict__ msum,
                                                const float* __restrict__ Bc,
                                                const float* __restrict__ gamma,
                                                const float* __restrict__ beta,
                                                float* __restrict__ rr,
                                                float* __restrict__ tmpBN){
    __shared__ float redM[192];
    __shared__ float redV[192];
    int c = blockIdx.x, d = threadIdx.x;
    const float invN = 1.f / (float)N_NODES;
    float m = bf2f(MT[(long)c*KDIM + d]);
    long vi = (long)c*KDIM + d;
    float vsum = Vp[vi] + Vp[vi + HIDDEN*KDIM] + Vp[vi + 2*HIDDEN*KDIM]
               + Vp[vi + 3*HIDDEN*KDIM];
    redM[d] = msum[d]*invN * m;
    redV[d] = vsum * m;
    __syncthreads();
    for (int off = 96; off >= 3; off >>= 1){
        if (d < off){ redM[d] += redM[d + off]; redV[d] += redV[d + off]; }
        __syncthreads();
    }
    if (d == 0){
        float mu  = Bc[c] + redM[0] + redM[1] + redM[2];
        float var = redV[0] + redV[1] + redV[2];
        float r = gamma[c] * rsqrtf(var + 1e-5f);
        rr[c] = r;
        tmpBN[c] = r * (Bc[c] - mu) + beta[c];
    }
}

// ---- 11b. cvec[o] = sum_k q_k tmpBN[k*64+o] ----
__global__ void k_solveB(const float* __restrict__ tmpBN, const float* __restrict__ q,
                         float* __restrict__ cvec){
    int c = threadIdx.x;   // 0..63
    float s = 0.f;
    #pragma unroll
    for (int k = 0; k < 8; ++k) s += q[k] * tmpBN[k*64 + c];
    cvec[c] = s;
}

// ---- 12. fold rho into M: GT[o][d] = sum_k q_k r_{k64+o} MT[k64+o][d] ----
__global__ void k_buildG(const ushort* __restrict__ MT, const float* __restrict__ rr,
                         const float* __restrict__ q, ushort* __restrict__ GT){
    int o = blockIdx.x, d = threadIdx.x;  // 64 x 192
    float s = 0.f;
    #pragma unroll
    for (int k = 0; k < 8; ++k)
        s += q[k] * rr[k*64 + o] * bf2f(MT[(k*64 + o)*KDIM + d]);
    GT[o*KDIM + d] = f2bf(s);
}

// ---- 13. out = H @ GT^T + cvec ----
#define LDA 200
__global__ __launch_bounds__(256) void k_outgemm(const ushort* __restrict__ H,
                                                 const ushort* __restrict__ GT,
                                                 const float* __restrict__ cvec,
                                                 float* __restrict__ out){
    __shared__ ushort As[128*LDA];
    __shared__ ushort Gs[64*LDA];
    int t = threadIdx.x;
    int n0 = blockIdx.x * 128;
    int w = t >> 6, lane = t & 63;
    int m16 = lane & 15, quad = lane >> 4;
    int wr = w * 32;
    float4v acc[2][4] = {};
    #pragma unroll
    for (int it = 0; it < 12; ++it){
        int flat = it*256 + t;               // 128 rows * 24 segs
        int row = flat / 24, seg = flat - row*24;
        int gr = n0 + row;
        short8 v = {0,0,0,0,0,0,0,0};
        if (gr < N_NODES) v = *(const short8*)(H + (long)gr*KDIM + seg*8);
        *(short8*)(As + row*LDA + seg*8) = v;
    }
    #pragma unroll
    for (int it = 0; it < 6; ++it){
        int flat = it*256 + t;               // 64 rows * 24 segs
        int row = flat / 24, seg = flat - row*24;
        short8 v = *(const short8*)(GT + row*KDIM + seg*8);
        *(short8*)(Gs + row*LDA + seg*8) = v;
    }
    __syncthreads();
    #pragma unroll
    for (int kk = 0; kk < 192; kk += 32){
        short8 af[2], bf[4];
        #pragma unroll
        for (int i = 0; i < 2; ++i)
            af[i] = *(const short8*)(As + (wr + i*16 + m16)*LDA + kk + quad*8);
        #pragma unroll
        for (int j = 0; j < 4; ++j)
            bf[j] = *(const short8*)(Gs + (j*16 + m16)*LDA + kk + quad*8);
        #pragma unroll
        for (int i = 0; i < 2; ++i)
            #pragma unroll
            for (int j = 0; j < 4; ++j)
                acc[i][j] = __builtin_amdgcn_mfma_f32_16x16x32_bf16(af[i], bf[j], acc[i][j], 0,0,0);
    }
    #pragma unroll
    for (int i = 0; i < 2; ++i)
        #pragma unroll
        for (int j = 0; j < 4; ++j)
            #pragma unroll
            for (int r = 0; r < 4; ++r){
                int rowg = n0 + wr + i*16 + quad*4 + r;
                int o = j*16 + m16;
                if (rowg < N_NODES) out[(long)rowg*64 + o] = acc[i][j][r] + cvec[o];
            }
}

extern "C" void kernel_launch(void* const* d_in, const int* in_sizes, int n_in,
                              void* d_out, int out_size, void* d_ws, size_t ws_size,
                              hipStream_t stream) {
    const float* feats = (const float*)d_in[0];
    const int*   src   = (const int*)  d_in[1];
    const int*   dst   = (const int*)  d_in[2];
    const float* W0    = (const float*)d_in[3];
    const float* b0    = (const float*)d_in[4];
    const float* W1    = (const float*)d_in[5];
    const float* b1    = (const float*)d_in[6];
    const float* W2    = (const float*)d_in[7];
    const float* b2    = (const float*)d_in[8];
    const float* fcW   = (const float*)d_in[9];
    const float* fcb   = (const float*)d_in[10];
    const float* gamma = (const float*)d_in[11];
    const float* beta  = (const float*)d_in[12];
    const float* q     = (const float*)d_in[13];
    float* out = (float*)d_out;

    char* ws = (char*)d_ws;
    size_t off = 0;
    auto alloc = [&](size_t bytes) -> char* {
        char* p = ws + off;
        off = (off + bytes + 511) & ~(size_t)511;
        return p;
    };
    uint*   histA   = (uint*)  alloc((size_t)NB * NSLICE * 4);
    uint*   sbase   = (uint*)  alloc((size_t)NB * NSLICE * 4);
    uint*   btot    = (uint*)  alloc((size_t)NB * 4);
    uint*   bstart  = (uint*)  alloc((size_t)NB * 4);
    uint*   rec     = (uint*)  alloc((size_t)N_EDGES * 4);
    int*    deg     = (int*)   alloc((size_t)N_NODES * 4);
    int*    rowptr  = (int*)   alloc((size_t)N_NODES * 4);
    float*  nrm     = (float*) alloc((size_t)N_NODES * 4);
    int*    csr     = (int*)   alloc((size_t)N_EDGES * 4);
    ushort* Hx      = (ushort*)alloc((size_t)N_NODES * 64 * 2);
    ushort* HsB     = (ushort*)alloc((size_t)N_NODES * 64 * 2);
    ushort* H       = (ushort*)alloc((size_t)N_NODES * KDIM * 2);
    ushort* MT      = (ushort*)alloc((size_t)HIDDEN * KDIM * 2);
    float*  MTp     = (float*) alloc((size_t)8 * HIDDEN * KDIM * 4);
    float*  Bc      = (float*) alloc((size_t)HIDDEN * 4);
    float*  msum    = (float*) alloc((size_t)KDIM * 4);
    uint*   P       = (uint*)  alloc((size_t)NPART * PPB * 4);
    float*  SP      = (float*) alloc((size_t)NSPLIT * NPAIR * 256 * 4);
    float*  C       = (float*) alloc((size_t)SDIM * 4);
    float*  Vp      = (float*) alloc((size_t)4 * HIDDEN * KDIM * 4);
    float*  rr      = (float*) alloc((size_t)HIDDEN * 4);
    float*  tmpBN   = (float*) alloc((size_t)HIDDEN * 4);
    float*  cvec    = (float*) alloc((size_t)64 * 4);
    ushort* GT      = (ushort*)alloc((size_t)64 * KDIM * 2);
    (void)ws_size; (void)n_in; (void)in_sizes; (void)out_size;

    hipMemsetAsync(msum, 0, (size_t)KDIM * 4, stream);

    k_histA <<<NSLICE, 1024, 0, stream>>>(dst, histA);
    k_scanSl<<<NB, 256, 0, stream>>>(histA, sbase, btot);
    k_scanBk<<<1, 512, 0, stream>>>(btot, bstart);
    k_packA <<<NSLICE, 1024, 0, stream>>>(src, dst, sbase, bstart, rec);
    k_passB <<<NB, 256, 0, stream>>>(rec, bstart, btot, csr, deg, rowptr, nrm);

    k_cast  <<<(N_NODES*16 + 255)/256, 256, 0, stream>>>(feats, nrm, Hx);

    int aggGrid = (N_NODES + 7) / 8;
    k_agg<true> <<<aggGrid, 256, 0, stream>>>(Hx,  H, 0,   HsB, rowptr, deg, nrm, csr);
    k_agg<true> <<<aggGrid, 256, 0, stream>>>(HsB, H, 64,  Hx,  rowptr, deg, nrm, csr);
    k_agg<false><<<aggGrid, 256, 0, stream>>>(Hx,  H, 128, HsB, rowptr, deg, nrm, csr);

    dim3 pmGrid(8, HIDDEN/4);
    k_prepM1<<<pmGrid, 192, 0, stream>>>(W0, W1, W2, fcW, MTp);
    k_prepM2<<<(HIDDEN*KDIM + 255)/256, 256, 0, stream>>>(MTp, MT);
    k_bias <<<HIDDEN, 256, 0, stream>>>(b0, b1, b2, fcW, fcb, Bc);

    k_hth   <<<NPART, 256, 0, stream>>>(H, P, msum);
    dim3 rGrid(PPB/256, NSPLIT);
    k_reduce<<<rGrid, 256, 0, stream>>>(P, SP);
    k_finC  <<<NPAIR, 256, 0, stream>>>(SP, msum, C);
    dim3 cvGrid(4, HIDDEN/4);
    k_cv1   <<<cvGrid, 192, 0, stream>>>(C, MT, Vp);
    k_solveA<<<HIDDEN, 192, 0, stream>>>(Vp, MT, msum, Bc, gamma, beta, rr, tmpBN);
    k_solveB<<<1, 64, 0, stream>>>(tmpBN, q, cvec);
    k_buildG<<<64, KDIM, 0, stream>>>(MT, rr, q, GT);

    k_outgemm<<<NCHUNK, 256, 0, stream>>>(H, GT, cvec, out);
}

// Round 8
// 349.987 us; speedup vs baseline: 1.0856x; 1.0347x over previous
//
#include <hip/hip_runtime.h>
#include <hip/hip_bf16.h>
#include <stdint.h>

typedef unsigned short ushort;
typedef unsigned int uint;
typedef unsigned char uchar;

#define N_NODES 100000
#define N_EDGES 1600000
#define KDIM 192      // 3 * 64 concatenated h_j
#define HIDDEN 512
#define NCHUNK 782    // ceil(N/128)
#define NCH 2         // chunks accumulated per k_hth block
#define NPART 391     // NCHUNK/NCH partial blocks
#define SDIM (KDIM*KDIM)
#define NPAIR 78      // 12*13/2 upper-triangle band pairs
#define PPB   9984    // uints per block partial: 78 frags * 128 uints
#define NSPLIT 8
#define LDT 194       // ushort stride of node-major LDS tile (192 + 2 pad)
#define NSLICE 256    // edge slices
#define EPS (N_EDGES/NSLICE)   // 6250 edges per slice

// ---- bucket sort params: bucket = dst>>8 (256 nodes per bucket) ----
#define NB 391        // ceil(100000/256)
#define BCAP 5120     // LDS record capacity per bucket (mean 4096, sd 64)

typedef __attribute__((ext_vector_type(8))) short short8;
typedef __attribute__((ext_vector_type(4))) short short4v;
typedef __attribute__((ext_vector_type(4))) uint uint4v;
typedef __attribute__((ext_vector_type(4))) float float4v;
typedef __attribute__((ext_vector_type(2))) float float2v;
typedef __attribute__((ext_vector_type(2))) uint uint2v;

__device__ __forceinline__ float bf2f(ushort u){
    uint x = ((uint)u) << 16;
    return __builtin_bit_cast(float, x);
}
__device__ __forceinline__ float bflo(uint u){
    return __builtin_bit_cast(float, u << 16);
}
__device__ __forceinline__ float bfhi(uint u){
    return __builtin_bit_cast(float, u & 0xffff0000u);
}
__device__ __forceinline__ ushort f2bf(float f){
    uint u = __builtin_bit_cast(uint, f);
    u += 0x7fffu + ((u >> 16) & 1u);   // round-to-nearest-even
    return (ushort)(u >> 16);
}

// ---- 1. per-slice bucket histogram (391 LDS counters) ----
__global__ __launch_bounds__(1024) void k_histA(const int* __restrict__ dst,
                                                uint* __restrict__ histA){
    __shared__ uint cnt[NB];
    int slice = blockIdx.x, t = threadIdx.x;
    for (int b = t; b < NB; b += 1024) cnt[b] = 0;
    __syncthreads();
    int e0 = slice * EPS;
    for (int i = t; i < EPS; i += 1024){
        uint d = (uint)dst[e0 + i];
        atomicAdd(&cnt[d >> 8], 1u);
    }
    __syncthreads();
    for (int b = t; b < NB; b += 1024) histA[(size_t)b*NSLICE + slice] = cnt[b];
}

// ---- 1b. per-bucket scan over slices -> slice bases + bucket totals ----
__global__ void k_scanSl(const uint* __restrict__ histA, uint* __restrict__ sbase,
                         uint* __restrict__ btot){
    __shared__ uint sc[NSLICE];
    int b = blockIdx.x, t = threadIdx.x;
    uint v = histA[(size_t)b*NSLICE + t];
    sc[t] = v; __syncthreads();
    for (int off = 1; off < 256; off <<= 1){
        uint u = (t >= off) ? sc[t - off] : 0;
        __syncthreads();
        sc[t] += u;
        __syncthreads();
    }
    sbase[(size_t)b*NSLICE + t] = sc[t] - v;
    if (t == 255) btot[b] = sc[255];
}

// ---- 1c. exclusive scan of bucket totals -> bucket starts ----
__global__ void k_scanBk(const uint* __restrict__ btot, uint* __restrict__ bstart){
    __shared__ uint sc[512];
    int t = threadIdx.x;
    uint v = (t < NB) ? btot[t] : 0;
    sc[t] = v; __syncthreads();
    for (int off = 1; off < 512; off <<= 1){
        uint u = (t >= off) ? sc[t - off] : 0;
        __syncthreads();
        sc[t] += u;
        __syncthreads();
    }
    if (t < NB) bstart[t] = sc[t] - v;
}

// ---- 2. pack records bucket-major; slot via LDS running offsets ----
__global__ __launch_bounds__(1024) void k_packA(const int* __restrict__ src,
                                                const int* __restrict__ dst,
                                                const uint* __restrict__ sbase,
                                                const uint* __restrict__ bstart,
                                                uint* __restrict__ rec){
    __shared__ uint arr[NB];
    int slice = blockIdx.x, t = threadIdx.x;
    for (int b = t; b < NB; b += 1024)
        arr[b] = bstart[b] + sbase[(size_t)b*NSLICE + slice];
    __syncthreads();
    int e0 = slice * EPS;
    for (int i = t; i < EPS; i += 1024){
        int e = e0 + i;
        uint d = (uint)dst[e];
        uint bk = d >> 8;
        uint slot = atomicAdd(&arr[bk], 1u);
        rec[slot] = (uint)src[e] | ((d & 255u) << 17);
    }
}

// ---- 3. per-bucket: count, scan, emit deg/rowptr/nrm + csr, then cast feats ----
__global__ __launch_bounds__(256) void k_passB(const uint* __restrict__ rec,
                                               const uint* __restrict__ bstart,
                                               const uint* __restrict__ btot,
                                               const float* __restrict__ feats,
                                               int* __restrict__ csr,
                                               int* __restrict__ deg,
                                               int* __restrict__ rowptr,
                                               float* __restrict__ nrm,
                                               ushort* __restrict__ Hx){
    __shared__ uint recs[BCAP];
    __shared__ uint cntL[256];
    __shared__ uint ofs[256];
    __shared__ float nrmL[256];
    int b = blockIdx.x, t = threadIdx.x;
    uint base = bstart[b], cnt = btot[b];
    cntL[t] = 0;
    __syncthreads();
    for (uint i = t; i < cnt; i += 256){
        uint rv = rec[base + i];
        if (i < BCAP) recs[i] = rv;
        atomicAdd(&cntL[(rv >> 17) & 255u], 1u);
    }
    __syncthreads();
    uint c = cntL[t];
    ofs[t] = c; __syncthreads();
    for (int off = 1; off < 256; off <<= 1){
        uint u = (t >= off) ? ofs[t - off] : 0;
        __syncthreads();
        ofs[t] += u;
        __syncthreads();
    }
    uint excl = ofs[t] - c;
    int node = b*256 + t;
    float nv = rsqrtf((float)(c > 0 ? c : 1));
    nrmL[t] = nv;
    if (node < N_NODES){
        deg[node] = (int)c;
        rowptr[node] = (int)(base + excl);
        nrm[node] = nv;
    }
    __syncthreads();
    ofs[t] = excl;
    __syncthreads();
    for (uint i = t; i < cnt; i += 256){
        uint rv = (i < BCAP) ? recs[i] : rec[base + i];
        uint n = (rv >> 17) & 255u;
        uint p = atomicAdd(&ofs[n], 1u);
        csr[base + p] = (int)(rv & 0x1FFFFu);
    }
    // fused cast: this block's 256 nodes, feats f32 -> bf16 * nrm
    int nodeBase = b*256;
    for (int g = t; g < 256*16; g += 256){
        int ln = g >> 4;
        int nd = nodeBase + ln;
        if (nd < N_NODES){
            float w = nrmL[ln];
            float4v v = ((const float4v*)feats)[(long)nd*16 + (g & 15)];
            short4v o;
            o[0] = (short)f2bf(v[0]*w); o[1] = (short)f2bf(v[1]*w);
            o[2] = (short)f2bf(v[2]*w); o[3] = (short)f2bf(v[3]*w);
            ((short4v*)Hx)[(long)nd*16 + (g & 15)] = o;
        }
    }
}

// ---- 5. aggregation: 2 nodes per wave; deg<=32 path with UNCONDITIONAL
//      clamped gathers (8 csr loads + 8 row gathers all in flight) ----
template<bool WRITE_HS>
__global__ __launch_bounds__(256, 4) void k_agg(const ushort* __restrict__ inp,
                      ushort* __restrict__ H, int outoff,
                      ushort* __restrict__ Hs,
                      const int* __restrict__ rowptr, const int* __restrict__ deg,
                      const float* __restrict__ nrm, const int* __restrict__ csr){
    int node = (blockIdx.x << 3) + (threadIdx.x >> 5);
    int lane = threadIdx.x & 63;
    if (node >= N_NODES) return;
    int slot = (lane & 31) >> 3;   // 0..3
    int fb   = lane & 7;
    int beg = rowptr[node];
    int d   = deg[node];
    float acc[8] = {};
    if (d > 0 && d <= 32){
        int emax = beg + d - 1;
        int idx[8];
        #pragma unroll
        for (int k = 0; k < 8; ++k){
            int e = beg + slot + k*4;
            idx[k] = csr[e < emax ? e : emax];
        }
        uint4v v[8];
        #pragma unroll
        for (int k = 0; k < 8; ++k)
            v[k] = *(const uint4v*)(inp + (long)idx[k]*64 + fb*8);
        #pragma unroll
        for (int k = 0; k < 8; ++k){
            if (slot + k*4 < d){
                #pragma unroll
                for (int p = 0; p < 4; ++p){
                    acc[2*p]   += bflo(v[k][p]);
                    acc[2*p+1] += bfhi(v[k][p]);
                }
            }
        }
    } else if (d > 32){
        int i = 0;
        for (; i + 8 <= d; i += 8){
            int sA = csr[beg + i + slot];
            int sB = csr[beg + i + 4 + slot];
            uint4v vA = *(const uint4v*)(inp + (long)sA*64 + fb*8);
            uint4v vB = *(const uint4v*)(inp + (long)sB*64 + fb*8);
            #pragma unroll
            for (int p = 0; p < 4; ++p){
                acc[2*p]   += bflo(vA[p]); acc[2*p+1] += bfhi(vA[p]);
                acc[2*p]   += bflo(vB[p]); acc[2*p+1] += bfhi(vB[p]);
            }
        }
        if (i + 4 <= d){
            int sA = csr[beg + i + slot];
            uint4v vA = *(const uint4v*)(inp + (long)sA*64 + fb*8);
            #pragma unroll
            for (int p = 0; p < 4; ++p){
                acc[2*p]   += bflo(vA[p]); acc[2*p+1] += bfhi(vA[p]);
            }
            i += 4;
        }
        if (i + slot < d){
            int s = csr[beg + i + slot];
            uint4v v = *(const uint4v*)(inp + (long)s*64 + fb*8);
            #pragma unroll
            for (int p = 0; p < 4; ++p){
                acc[2*p]   += bflo(v[p]); acc[2*p+1] += bfhi(v[p]);
            }
        }
    }
    #pragma unroll
    for (int k = 0; k < 8; ++k){
        acc[k] += __shfl_xor(acc[k], 8);
        acc[k] += __shfl_xor(acc[k], 16);
    }
    if (slot == 0){
        float wn = nrm[node];
        short8 o;
        #pragma unroll
        for (int k = 0; k < 8; ++k) o[k] = (short)f2bf(wn * acc[k]);
        *(short8*)(H + (long)node*KDIM + outoff + fb*8) = o;
        if (WRITE_HS){
            float w2 = wn * wn;
            short8 o2;
            #pragma unroll
            for (int k = 0; k < 8; ++k) o2[k] = (short)f2bf(w2 * acc[k]);
            *(short8*)(Hs + (long)node*64 + fb*8) = o2;
        }
    }
}

// ---- 6. fold weights, split-K x8, 4 c per block ----
__global__ __launch_bounds__(192) void k_prepM1(const float* __restrict__ W0,
                                                const float* __restrict__ W1,
                                                const float* __restrict__ W2,
                                                const float* __restrict__ fcW,
                                                float* __restrict__ MTp){
    int ks = blockIdx.x;          // 0..7
    int c0 = blockIdx.y * 4;      // 0..508
    int jd = threadIdx.x;         // 0..191
    int j = jd >> 6, d = jd & 63;
    const float* W  = (j == 0) ? W0 : (j == 1) ? W1 : W2;
    const float* wp = W + (ks*64)*64 + d;
    const float* f0 = fcW + (long)(c0+0)*1536 + j*512 + ks*64;
    const float* f1 = fcW + (long)(c0+1)*1536 + j*512 + ks*64;
    const float* f2 = fcW + (long)(c0+2)*1536 + j*512 + ks*64;
    const float* f3 = fcW + (long)(c0+3)*1536 + j*512 + ks*64;
    float a0 = 0.f, a1 = 0.f, a2 = 0.f, a3 = 0.f;
    #pragma unroll 8
    for (int k = 0; k < 64; ++k){
        float w = wp[k*64];
        a0 += w * f0[k]; a1 += w * f1[k]; a2 += w * f2[k]; a3 += w * f3[k];
    }
    long base = (long)ks*(HIDDEN*KDIM) + (long)c0*KDIM + jd;
    MTp[base]         = a0;
    MTp[base + KDIM]  = a1;
    MTp[base + 2*KDIM]= a2;
    MTp[base + 3*KDIM]= a3;
}

// ---- 6a2. sum 8 partials, cast to bf16 ----
__global__ void k_prepM2(const float* __restrict__ MTp, ushort* __restrict__ MT){
    int i = blockIdx.x*256 + threadIdx.x;   // 0..98303
    if (i >= HIDDEN*KDIM) return;
    float s = 0.f;
    #pragma unroll
    for (int ks = 0; ks < 8; ++ks) s += MTp[(long)ks*(HIDDEN*KDIM) + i];
    MT[i] = f2bf(s);
}

// ---- 6b. folded bias: one block per channel, LDS reduce ----
__global__ __launch_bounds__(256) void k_bias(const float* __restrict__ b0,
                                              const float* __restrict__ b1,
                                              const float* __restrict__ b2,
                                              const float* __restrict__ fcW,
                                              const float* __restrict__ fcb,
                                              float* __restrict__ Bc){
    __shared__ float red[256];
    int c = blockIdx.x, t = threadIdx.x;
    const float* fw = fcW + (long)c*1536;
    float s = b0[t]*fw[t]          + b0[t+256]*fw[t+256]
            + b1[t]*fw[512+t]      + b1[t+256]*fw[512+t+256]
            + b2[t]*fw[1024+t]     + b2[t+256]*fw[1024+t+256];
    red[t] = s; __syncthreads();
    for (int off = 128; off > 0; off >>= 1){
        if (t < off) red[t] += red[t + off];
        __syncthreads();
    }
    if (t == 0) Bc[c] = fcb[c] + red[0];
}

// ---- 7. symmetric H^T H: node-major LDS, 78 upper-tri band pairs ----
// 4-wave blocks, (p&3)==w (20 acc max, VGPR ~128), NCH=2 chunks per block.
template<int W>
__device__ __forceinline__ void do_pairs(const short8* frag, float4v* acc){
    int p = 0, c = 0;
    #pragma unroll
    for (int i = 0; i < 12; ++i)
        #pragma unroll
        for (int j = i; j < 12; ++j){
            if ((p & 3) == W){
                acc[c] = __builtin_amdgcn_mfma_f32_16x16x32_bf16(frag[i], frag[j], acc[c], 0,0,0);
                ++c;
            }
            ++p;
        }
}
template<int W>
__device__ __forceinline__ void store_pairs(const float4v* acc, uint* Pb, int lane){
    int p = 0, c = 0;
    #pragma unroll
    for (int i = 0; i < 12; ++i)
        #pragma unroll
        for (int j = i; j < 12; ++j){
            if ((p & 3) == W){
                uint2v v;
                v[0] = (uint)f2bf(acc[c][0]) | ((uint)f2bf(acc[c][1]) << 16);
                v[1] = (uint)f2bf(acc[c][2]) | ((uint)f2bf(acc[c][3]) << 16);
                *(uint2v*)(Pb + p*128 + lane*2) = v;
                ++c;
            }
            ++p;
        }
}

__global__ __launch_bounds__(256, 2) void k_hth(const ushort* __restrict__ H,
                                                uint* __restrict__ P,
                                                float* __restrict__ msum){
    __shared__ ushort Ts[128*LDT];   // 49664 B, node-major
    int t = threadIdx.x;
    int w = t >> 6, lane = t & 63;
    int m16 = lane & 15, quad = lane >> 4;
    float4v acc[20] = {};
    #pragma unroll
    for (int cc = 0; cc < NCH; ++cc){
        int chunk = blockIdx.x * NCH + cc;
        int n0 = chunk * 128;
        #pragma unroll
        for (int it = 0; it < 12; ++it){
            int flat = it*256 + t;           // 128 rows * 24 segs
            int row = flat / 24, seg = flat - row*24;
            int gr = n0 + row;
            short8 v = {0,0,0,0,0,0,0,0};
            if (gr < N_NODES) v = *(const short8*)(H + (long)gr*KDIM + seg*8);
            *(short8*)(Ts + row*LDT + seg*8) = v;
        }
        __syncthreads();
        #pragma unroll
        for (int kt = 0; kt < 4; ++kt){
            short8 frag[12];
            #pragma unroll
            for (int b = 0; b < 12; ++b){
                short8 f;
                #pragma unroll
                for (int j = 0; j < 8; ++j)
                    f[j] = (short)Ts[(kt*32 + quad*8 + j)*LDT + b*16 + m16];
                frag[b] = f;
            }
            if      (w == 0) do_pairs<0>(frag, acc);
            else if (w == 1) do_pairs<1>(frag, acc);
            else if (w == 2) do_pairs<2>(frag, acc);
            else             do_pairs<3>(frag, acc);
        }
        // folded column sums (Ts untouched since staging)
        if (t < KDIM){
            float s = 0.f;
            #pragma unroll 4
            for (int n = 0; n < 128; ++n) s += bf2f(Ts[n*LDT + t]);
            atomicAdd(&msum[t], s);
        }
        __syncthreads();
    }
    uint* Pb = P + (long)blockIdx.x * PPB;
    if      (w == 0) store_pairs<0>(acc, Pb, lane);
    else if (w == 1) store_pairs<1>(acc, Pb, lane);
    else if (w == 2) store_pairs<2>(acc, Pb, lane);
    else             store_pairs<3>(acc, Pb, lane);
}

// ---- 8. split-K reduce of partials (coalesced) ----
__global__ void k_reduce(const uint* __restrict__ P, float* __restrict__ SP){
    int p = blockIdx.x * 256 + threadIdx.x;   // 0..9983
    int y = blockIdx.y;
    int b0 = y * 49, b1 = min(b0 + 49, NPART);
    float lo = 0.f, hi = 0.f;
    for (int b = b0; b < b1; ++b){
        uint v = P[(long)b*PPB + p];
        lo += bf2f((ushort)(v & 0xffff));
        hi += bf2f((ushort)(v >> 16));
    }
    float2v o; o[0] = lo; o[1] = hi;
    *(float2v*)(SP + (long)y*(NPAIR*256) + p*2) = o;
}

// ---- 9. finalize covariance C (both triangles) from fragment layout ----
__global__ void k_finC(const float* __restrict__ SP, const float* __restrict__ msum,
                       float* __restrict__ C){
    int idx = blockIdx.x * 256 + threadIdx.x;   // 0..19967
    float s = 0.f;
    #pragma unroll
    for (int y = 0; y < NSPLIT; ++y) s += SP[(long)y*(NPAIR*256) + idx];
    int h = idx & 1, pu = idx >> 1;
    int p = pu >> 7, rem = pu & 127;
    int l = rem >> 1, u = rem & 1;
    int r = u*2 + h;
    int pi = 0, pj = 0, off = 0;
    #pragma unroll
    for (int k = 0; k < 12; ++k){
        int len = 12 - k;
        if (p >= off && p < off + len){ pi = k; pj = k + (p - off); }
        off += len;
    }
    int m = pi*16 + (l >> 4)*4 + r;
    int n = pj*16 + (l & 15);
    const float invN = 1.f / (float)N_NODES;
    float v = s*invN - (msum[m]*invN)*(msum[n]*invN);
    C[m*KDIM + n] = v;
    C[n*KDIM + m] = v;
}

// ---- 10. Vp[ks][c][d] = partial C @ M_c over K-slice ks (split-K x4, 4c/block) ----
__global__ __launch_bounds__(192) void k_cv1(const float* __restrict__ C,
                                             const ushort* __restrict__ MT,
                                             float* __restrict__ Vp){
    int ks = blockIdx.x;          // 0..3, 48-wide K slice
    int c0 = blockIdx.y * 4;      // 0..508
    int d  = threadIdx.x;         // 0..191
    const ushort* m0 = MT + (long)(c0+0)*KDIM + ks*48;
    const ushort* m1 = MT + (long)(c0+1)*KDIM + ks*48;
    const ushort* m2 = MT + (long)(c0+2)*KDIM + ks*48;
    const ushort* m3 = MT + (long)(c0+3)*KDIM + ks*48;
    const float* cp = C + (long)(ks*48)*KDIM + d;
    float a0 = 0.f, a1 = 0.f, a2 = 0.f, a3 = 0.f;
    #pragma unroll 8
    for (int k = 0; k < 48; ++k){
        float cv = cp[(long)k*KDIM];
        a0 += bf2f(m0[k]) * cv; a1 += bf2f(m1[k]) * cv;
        a2 += bf2f(m2[k]) * cv; a3 += bf2f(m3[k]) * cv;
    }
    long base = (long)ks*(HIDDEN*KDIM) + (long)c0*KDIM + d;
    Vp[base]          = a0;
    Vp[base + KDIM]   = a1;
    Vp[base + 2*KDIM] = a2;
    Vp[base + 3*KDIM] = a3;
}

// ---- 11a. BN solve per channel: rr[c], tmpBN[c] (512 blocks, LDS reduce) ----
__global__ __launch_bounds__(192) void k_solveA(const float* __restrict__ Vp,
                                                const ushort* __restrict__ MT,
                                                const float* __restrict__ msum,
                                                const float* __restrict__ Bc,
                                                const float* __restrict__ gamma,
                                                const float* __restrict__ beta,
                                                float* __restrict__ rr,
                                                float* __restrict__ tmpBN){
    __shared__ float redM[192];
    __shared__ float redV[192];
    int c = blockIdx.x, d = threadIdx.x;
    const float invN = 1.f / (float)N_NODES;
    float m = bf2f(MT[(long)c*KDIM + d]);
    long vi = (long)c*KDIM + d;
    float vsum = Vp[vi] + Vp[vi + HIDDEN*KDIM] + Vp[vi + 2*HIDDEN*KDIM]
               + Vp[vi + 3*HIDDEN*KDIM];
    redM[d] = msum[d]*invN * m;
    redV[d] = vsum * m;
    __syncthreads();
    for (int off = 96; off >= 3; off >>= 1){
        if (d < off){ redM[d] += redM[d + off]; redV[d] += redV[d + off]; }
        __syncthreads();
    }
    if (d == 0){
        float mu  = Bc[c] + redM[0] + redM[1] + redM[2];
        float var = redV[0] + redV[1] + redV[2];
        float r = gamma[c] * rsqrtf(var + 1e-5f);
        rr[c] = r;
        tmpBN[c] = r * (Bc[c] - mu) + beta[c];
    }
}

// ---- 12. fold rho into M (+ block 0 computes cvec) ----
__global__ void k_buildG(const ushort* __restrict__ MT, const float* __restrict__ rr,
                         const float* __restrict__ q, const float* __restrict__ tmpBN,
                         ushort* __restrict__ GT, float* __restrict__ cvec){
    int o = blockIdx.x, d = threadIdx.x;  // 64 x 192
    float s = 0.f;
    #pragma unroll
    for (int k = 0; k < 8; ++k)
        s += q[k] * rr[k*64 + o] * bf2f(MT[(k*64 + o)*KDIM + d]);
    GT[o*KDIM + d] = f2bf(s);
    if (o == 0 && d < 64){
        float cs = 0.f;
        #pragma unroll
        for (int k = 0; k < 8; ++k) cs += q[k] * tmpBN[k*64 + d];
        cvec[d] = cs;
    }
}

// ---- 13. out = H @ GT^T + cvec ----
#define LDA 200
__global__ __launch_bounds__(256) void k_outgemm(const ushort* __restrict__ H,
                                                 const ushort* __restrict__ GT,
                                                 const float* __restrict__ cvec,
                                                 float* __restrict__ out){
    __shared__ ushort As[128*LDA];
    __shared__ ushort Gs[64*LDA];
    int t = threadIdx.x;
    int n0 = blockIdx.x * 128;
    int w = t >> 6, lane = t & 63;
    int m16 = lane & 15, quad = lane >> 4;
    int wr = w * 32;
    float4v acc[2][4] = {};
    #pragma unroll
    for (int it = 0; it < 12; ++it){
        int flat = it*256 + t;               // 128 rows * 24 segs
        int row = flat / 24, seg = flat - row*24;
        int gr = n0 + row;
        short8 v = {0,0,0,0,0,0,0,0};
        if (gr < N_NODES) v = *(const short8*)(H + (long)gr*KDIM + seg*8);
        *(short8*)(As + row*LDA + seg*8) = v;
    }
    #pragma unroll
    for (int it = 0; it < 6; ++it){
        int flat = it*256 + t;               // 64 rows * 24 segs
        int row = flat / 24, seg = flat - row*24;
        short8 v = *(const short8*)(GT + row*KDIM + seg*8);
        *(short8*)(Gs + row*LDA + seg*8) = v;
    }
    __syncthreads();
    #pragma unroll
    for (int kk = 0; kk < 192; kk += 32){
        short8 af[2], bf[4];
        #pragma unroll
        for (int i = 0; i < 2; ++i)
            af[i] = *(const short8*)(As + (wr + i*16 + m16)*LDA + kk + quad*8);
        #pragma unroll
        for (int j = 0; j < 4; ++j)
            bf[j] = *(const short8*)(Gs + (j*16 + m16)*LDA + kk + quad*8);
        #pragma unroll
        for (int i = 0; i < 2; ++i)
            #pragma unroll
            for (int j = 0; j < 4; ++j)
                acc[i][j] = __builtin_amdgcn_mfma_f32_16x16x32_bf16(af[i], bf[j], acc[i][j], 0,0,0);
    }
    #pragma unroll
    for (int i = 0; i < 2; ++i)
        #pragma unroll
        for (int j = 0; j < 4; ++j)
            #pragma unroll
            for (int r = 0; r < 4; ++r){
                int rowg = n0 + wr + i*16 + quad*4 + r;
                int o = j*16 + m16;
                if (rowg < N_NODES) out[(long)rowg*64 + o] = acc[i][j][r] + cvec[o];
            }
}

extern "C" void kernel_launch(void* const* d_in, const int* in_sizes, int n_in,
                              void* d_out, int out_size, void* d_ws, size_t ws_size,
                              hipStream_t stream) {
    const float* feats = (const float*)d_in[0];
    const int*   src   = (const int*)  d_in[1];
    const int*   dst   = (const int*)  d_in[2];
    const float* W0    = (const float*)d_in[3];
    const float* b0    = (const float*)d_in[4];
    const float* W1    = (const float*)d_in[5];
    const float* b1    = (const float*)d_in[6];
    const float* W2    = (const float*)d_in[7];
    const float* b2    = (const float*)d_in[8];
    const float* fcW   = (const float*)d_in[9];
    const float* fcb   = (const float*)d_in[10];
    const float* gamma = (const float*)d_in[11];
    const float* beta  = (const float*)d_in[12];
    const float* q     = (const float*)d_in[13];
    float* out = (float*)d_out;

    char* ws = (char*)d_ws;
    size_t off = 0;
    auto alloc = [&](size_t bytes) -> char* {
        char* p = ws + off;
        off = (off + bytes + 511) & ~(size_t)511;
        return p;
    };
    uint*   histA   = (uint*)  alloc((size_t)NB * NSLICE * 4);
    uint*   sbase   = (uint*)  alloc((size_t)NB * NSLICE * 4);
    uint*   btot    = (uint*)  alloc((size_t)NB * 4);
    uint*   bstart  = (uint*)  alloc((size_t)NB * 4);
    uint*   rec     = (uint*)  alloc((size_t)N_EDGES * 4);
    int*    deg     = (int*)   alloc((size_t)N_NODES * 4);
    int*    rowptr  = (int*)   alloc((size_t)N_NODES * 4);
    float*  nrm     = (float*) alloc((size_t)N_NODES * 4);
    int*    csr     = (int*)   alloc((size_t)N_EDGES * 4);
    ushort* Hx      = (ushort*)alloc((size_t)N_NODES * 64 * 2);
    ushort* HsB     = (ushort*)alloc((size_t)N_NODES * 64 * 2);
    ushort* H       = (ushort*)alloc((size_t)N_NODES * KDIM * 2);
    ushort* MT      = (ushort*)alloc((size_t)HIDDEN * KDIM * 2);
    float*  MTp     = (float*) alloc((size_t)8 * HIDDEN * KDIM * 4);
    float*  Bc      = (float*) alloc((size_t)HIDDEN * 4);
    float*  msum    = (float*) alloc((size_t)KDIM * 4);
    uint*   P       = (uint*)  alloc((size_t)NPART * PPB * 4);
    float*  SP      = (float*) alloc((size_t)NSPLIT * NPAIR * 256 * 4);
    float*  C       = (float*) alloc((size_t)SDIM * 4);
    float*  Vp      = (float*) alloc((size_t)4 * HIDDEN * KDIM * 4);
    float*  rr      = (float*) alloc((size_t)HIDDEN * 4);
    float*  tmpBN   = (float*) alloc((size_t)HIDDEN * 4);
    float*  cvec    = (float*) alloc((size_t)64 * 4);
    ushort* GT      = (ushort*)alloc((size_t)64 * KDIM * 2);
    (void)ws_size; (void)n_in; (void)in_sizes; (void)out_size;

    hipMemsetAsync(msum, 0, (size_t)KDIM * 4, stream);

    k_histA <<<NSLICE, 1024, 0, stream>>>(dst, histA);
    k_scanSl<<<NB, 256, 0, stream>>>(histA, sbase, btot);
    k_scanBk<<<1, 512, 0, stream>>>(btot, bstart);
    k_packA <<<NSLICE, 1024, 0, stream>>>(src, dst, sbase, bstart, rec);
    k_passB <<<NB, 256, 0, stream>>>(rec, bstart, btot, feats, csr, deg, rowptr, nrm, Hx);

    int aggGrid = (N_NODES + 7) / 8;
    k_agg<true> <<<aggGrid, 256, 0, stream>>>(Hx,  H, 0,   HsB, rowptr, deg, nrm, csr);
    k_agg<true> <<<aggGrid, 256, 0, stream>>>(HsB, H, 64,  Hx,  rowptr, deg, nrm, csr);
    k_agg<false><<<aggGrid, 256, 0, stream>>>(Hx,  H, 128, HsB, rowptr, deg, nrm, csr);

    dim3 pmGrid(8, HIDDEN/4);
    k_prepM1<<<pmGrid, 192, 0, stream>>>(W0, W1, W2, fcW, MTp);
    k_prepM2<<<(HIDDEN*KDIM + 255)/256, 256, 0, stream>>>(MTp, MT);
    k_bias <<<HIDDEN, 256, 0, stream>>>(b0, b1, b2, fcW, fcb, Bc);

    k_hth   <<<NPART, 256, 0, stream>>>(H, P, msum);
    dim3 rGrid(PPB/256, NSPLIT);
    k_reduce<<<rGrid, 256, 0, stream>>>(P, SP);
    k_finC  <<<NPAIR, 256, 0, stream>>>(SP, msum, C);
    dim3 cvGrid(4, HIDDEN/4);
    k_cv1   <<<cvGrid, 192, 0, stream>>>(C, MT, Vp);
    k_solveA<<<HIDDEN, 192, 0, stream>>>(Vp, MT, msum, Bc, gamma, beta, rr, tmpBN);
    k_buildG<<<64, KDIM, 0, stream>>>(MT, rr, q, tmpBN, GT, cvec);

    k_outgemm<<<NCHUNK, 256, 0, stream>>>(H, GT, cvec, out);
}

// Round 11
// 340.624 us; speedup vs baseline: 1.1154x; 1.0275x over previous
//
#include <hip/hip_runtime.h>
#include <hip/hip_bf16.h>
#include <stdint.h>

typedef unsigned short ushort;
typedef unsigned int uint;
typedef unsigned char uchar;

#define N_NODES 100000
#define N_EDGES 1600000
#define KDIM 192      // 3 * 64 concatenated h_j
#define HIDDEN 512
#define NCHUNK 782    // ceil(N/128)
#define NCH 2         // chunks accumulated per k_hth block
#define NPART 391     // NCHUNK/NCH partial blocks
#define SDIM (KDIM*KDIM)
#define NPAIR 78      // 12*13/2 upper-triangle band pairs
#define PPB   9984    // uints per block partial: 78 frags * 128 uints
#define NSPLIT 8
#define LDT 194       // ushort stride of node-major LDS tile (192 + 2 pad)
#define NSLICE 256    // edge slices
#define EPS (N_EDGES/NSLICE)   // 6250 edges per slice

// ---- bucket sort params: bucket = dst>>8 (256 nodes per bucket) ----
#define NB 391        // ceil(100000/256)
#define BCAP 5120     // LDS record capacity per bucket (mean 4096, sd 64)

typedef __attribute__((ext_vector_type(8))) short short8;
typedef __attribute__((ext_vector_type(4))) short short4v;
typedef __attribute__((ext_vector_type(4))) uint uint4v;
typedef __attribute__((ext_vector_type(4))) float float4v;
typedef __attribute__((ext_vector_type(2))) float float2v;
typedef __attribute__((ext_vector_type(2))) uint uint2v;

__device__ __forceinline__ float bf2f(ushort u){
    uint x = ((uint)u) << 16;
    return __builtin_bit_cast(float, x);
}
__device__ __forceinline__ float bflo(uint u){
    return __builtin_bit_cast(float, u << 16);
}
__device__ __forceinline__ float bfhi(uint u){
    return __builtin_bit_cast(float, u & 0xffff0000u);
}
__device__ __forceinline__ ushort f2bf(float f){
    uint u = __builtin_bit_cast(uint, f);
    u += 0x7fffu + ((u >> 16) & 1u);   // round-to-nearest-even
    return (ushort)(u >> 16);
}

// ---- 1. per-slice bucket histogram (391 LDS counters) ----
__global__ __launch_bounds__(1024) void k_histA(const int* __restrict__ dst,
                                                uint* __restrict__ histA){
    __shared__ uint cnt[NB];
    int slice = blockIdx.x, t = threadIdx.x;
    for (int b = t; b < NB; b += 1024) cnt[b] = 0;
    __syncthreads();
    int e0 = slice * EPS;
    for (int i = t; i < EPS; i += 1024){
        uint d = (uint)dst[e0 + i];
        atomicAdd(&cnt[d >> 8], 1u);
    }
    __syncthreads();
    for (int b = t; b < NB; b += 1024) histA[(size_t)b*NSLICE + slice] = cnt[b];
}

// ---- 1b. per-bucket scan over slices -> slice bases + bucket totals ----
__global__ void k_scanSl(const uint* __restrict__ histA, uint* __restrict__ sbase,
                         uint* __restrict__ btot){
    __shared__ uint sc[NSLICE];
    int b = blockIdx.x, t = threadIdx.x;
    uint v = histA[(size_t)b*NSLICE + t];
    sc[t] = v; __syncthreads();
    for (int off = 1; off < 256; off <<= 1){
        uint u = (t >= off) ? sc[t - off] : 0;
        __syncthreads();
        sc[t] += u;
        __syncthreads();
    }
    sbase[(size_t)b*NSLICE + t] = sc[t] - v;
    if (t == 255) btot[b] = sc[255];
}

// ---- 1c. exclusive scan of bucket totals -> bucket starts ----
__global__ void k_scanBk(const uint* __restrict__ btot, uint* __restrict__ bstart){
    __shared__ uint sc[512];
    int t = threadIdx.x;
    uint v = (t < NB) ? btot[t] : 0;
    sc[t] = v; __syncthreads();
    for (int off = 1; off < 512; off <<= 1){
        uint u = (t >= off) ? sc[t - off] : 0;
        __syncthreads();
        sc[t] += u;
        __syncthreads();
    }
    if (t < NB) bstart[t] = sc[t] - v;
}

// ---- 2. pack records bucket-major; slot via LDS running offsets ----
__global__ __launch_bounds__(1024) void k_packA(const int* __restrict__ src,
                                                const int* __restrict__ dst,
                                                const uint* __restrict__ sbase,
                                                const uint* __restrict__ bstart,
                                                uint* __restrict__ rec){
    __shared__ uint arr[NB];
    int slice = blockIdx.x, t = threadIdx.x;
    for (int b = t; b < NB; b += 1024)
        arr[b] = bstart[b] + sbase[(size_t)b*NSLICE + slice];
    __syncthreads();
    int e0 = slice * EPS;
    for (int i = t; i < EPS; i += 1024){
        int e = e0 + i;
        uint d = (uint)dst[e];
        uint bk = d >> 8;
        uint slot = atomicAdd(&arr[bk], 1u);
        rec[slot] = (uint)src[e] | ((d & 255u) << 17);
    }
}

// ---- 3. per-bucket: count, scan, emit deg/rowptr/nrm + csr, then cast feats ----
__global__ __launch_bounds__(256) void k_passB(const uint* __restrict__ rec,
                                               const uint* __restrict__ bstart,
                                               const uint* __restrict__ btot,
                                               const float* __restrict__ feats,
                                               int* __restrict__ csr,
                                               int* __restrict__ deg,
                                               int* __restrict__ rowptr,
                                               float* __restrict__ nrm,
                                               ushort* __restrict__ Hx){
    __shared__ uint recs[BCAP];
    __shared__ uint cntL[256];
    __shared__ uint ofs[256];
    __shared__ float nrmL[256];
    int b = blockIdx.x, t = threadIdx.x;
    uint base = bstart[b], cnt = btot[b];
    cntL[t] = 0;
    __syncthreads();
    for (uint i = t; i < cnt; i += 256){
        uint rv = rec[base + i];
        if (i < BCAP) recs[i] = rv;
        atomicAdd(&cntL[(rv >> 17) & 255u], 1u);
    }
    __syncthreads();
    uint c = cntL[t];
    ofs[t] = c; __syncthreads();
    for (int off = 1; off < 256; off <<= 1){
        uint u = (t >= off) ? ofs[t - off] : 0;
        __syncthreads();
        ofs[t] += u;
        __syncthreads();
    }
    uint excl = ofs[t] - c;
    int node = b*256 + t;
    float nv = rsqrtf((float)(c > 0 ? c : 1));
    nrmL[t] = nv;
    if (node < N_NODES){
        deg[node] = (int)c;
        rowptr[node] = (int)(base + excl);
        nrm[node] = nv;
    }
    __syncthreads();
    ofs[t] = excl;
    __syncthreads();
    for (uint i = t; i < cnt; i += 256){
        uint rv = (i < BCAP) ? recs[i] : rec[base + i];
        uint n = (rv >> 17) & 255u;
        uint p = atomicAdd(&ofs[n], 1u);
        csr[base + p] = (int)(rv & 0x1FFFFu);
    }
    // fused cast: this block's 256 nodes, feats f32 -> bf16 * nrm
    int nodeBase = b*256;
    for (int g = t; g < 256*16; g += 256){
        int ln = g >> 4;
        int nd = nodeBase + ln;
        if (nd < N_NODES){
            float w = nrmL[ln];
            float4v v = ((const float4v*)feats)[(long)nd*16 + (g & 15)];
            short4v o;
            o[0] = (short)f2bf(v[0]*w); o[1] = (short)f2bf(v[1]*w);
            o[2] = (short)f2bf(v[2]*w); o[3] = (short)f2bf(v[3]*w);
            ((short4v*)Hx)[(long)nd*16 + (g & 15)] = o;
        }
    }
}

// ---- 5. aggregation: 2 nodes per wave; deg<=32 path with grouped gathers:
//      k=0..3 always (covers d<=16, 55% of nodes), k=4..7 only when d>16 ----
template<bool WRITE_HS>
__global__ __launch_bounds__(256, 4) void k_agg(const ushort* __restrict__ inp,
                      ushort* __restrict__ H, int outoff,
                      ushort* __restrict__ Hs,
                      const int* __restrict__ rowptr, const int* __restrict__ deg,
                      const float* __restrict__ nrm, const int* __restrict__ csr){
    int node = (blockIdx.x << 3) + (threadIdx.x >> 5);
    int lane = threadIdx.x & 63;
    if (node >= N_NODES) return;
    int slot = (lane & 31) >> 3;   // 0..3
    int fb   = lane & 7;
    int beg = rowptr[node];
    int d   = deg[node];
    float acc[8] = {};
    if (d > 0 && d <= 32){
        int emax = beg + d - 1;
        uint4v v[8];
        int idx[4];
        #pragma unroll
        for (int k = 0; k < 4; ++k){
            int e = beg + slot + k*4;
            idx[k] = csr[e < emax ? e : emax];
        }
        #pragma unroll
        for (int k = 0; k < 4; ++k)
            v[k] = *(const uint4v*)(inp + (long)idx[k]*64 + fb*8);
        if (d > 16){
            int idx2[4];
            #pragma unroll
            for (int k = 0; k < 4; ++k){
                int e = beg + slot + (k+4)*4;
                idx2[k] = csr[e < emax ? e : emax];
            }
            #pragma unroll
            for (int k = 0; k < 4; ++k)
                v[4+k] = *(const uint4v*)(inp + (long)idx2[k]*64 + fb*8);
        }
        #pragma unroll
        for (int k = 0; k < 8; ++k){
            if (slot + k*4 < d){
                #pragma unroll
                for (int p = 0; p < 4; ++p){
                    acc[2*p]   += bflo(v[k][p]);
                    acc[2*p+1] += bfhi(v[k][p]);
                }
            }
        }
    } else if (d > 32){
        int i = 0;
        for (; i + 8 <= d; i += 8){
            int sA = csr[beg + i + slot];
            int sB = csr[beg + i + 4 + slot];
            uint4v vA = *(const uint4v*)(inp + (long)sA*64 + fb*8);
            uint4v vB = *(const uint4v*)(inp + (long)sB*64 + fb*8);
            #pragma unroll
            for (int p = 0; p < 4; ++p){
                acc[2*p]   += bflo(vA[p]); acc[2*p+1] += bfhi(vA[p]);
                acc[2*p]   += bflo(vB[p]); acc[2*p+1] += bfhi(vB[p]);
            }
        }
        if (i + 4 <= d){
            int sA = csr[beg + i + slot];
            uint4v vA = *(const uint4v*)(inp + (long)sA*64 + fb*8);
            #pragma unroll
            for (int p = 0; p < 4; ++p){
                acc[2*p]   += bflo(vA[p]); acc[2*p+1] += bfhi(vA[p]);
            }
            i += 4;
        }
        if (i + slot < d){
            int s = csr[beg + i + slot];
            uint4v v = *(const uint4v*)(inp + (long)s*64 + fb*8);
            #pragma unroll
            for (int p = 0; p < 4; ++p){
                acc[2*p]   += bflo(v[p]); acc[2*p+1] += bfhi(v[p]);
            }
        }
    }
    #pragma unroll
    for (int k = 0; k < 8; ++k){
        acc[k] += __shfl_xor(acc[k], 8);
        acc[k] += __shfl_xor(acc[k], 16);
    }
    if (slot == 0){
        float wn = nrm[node];
        short8 o;
        #pragma unroll
        for (int k = 0; k < 8; ++k) o[k] = (short)f2bf(wn * acc[k]);
        *(short8*)(H + (long)node*KDIM + outoff + fb*8) = o;
        if (WRITE_HS){
            float w2 = wn * wn;
            short8 o2;
            #pragma unroll
            for (int k = 0; k < 8; ++k) o2[k] = (short)f2bf(w2 * acc[k]);
            *(short8*)(Hs + (long)node*64 + fb*8) = o2;
        }
    }
}

// ---- 6. fold weights, split-K x8, 4 c per block ----
__global__ __launch_bounds__(192) void k_prepM1(const float* __restrict__ W0,
                                                const float* __restrict__ W1,
                                                const float* __restrict__ W2,
                                                const float* __restrict__ fcW,
                                                float* __restrict__ MTp){
    int ks = blockIdx.x;          // 0..7
    int c0 = blockIdx.y * 4;      // 0..508
    int jd = threadIdx.x;         // 0..191
    int j = jd >> 6, d = jd & 63;
    const float* W  = (j == 0) ? W0 : (j == 1) ? W1 : W2;
    const float* wp = W + (ks*64)*64 + d;
    const float* f0 = fcW + (long)(c0+0)*1536 + j*512 + ks*64;
    const float* f1 = fcW + (long)(c0+1)*1536 + j*512 + ks*64;
    const float* f2 = fcW + (long)(c0+2)*1536 + j*512 + ks*64;
    const float* f3 = fcW + (long)(c0+3)*1536 + j*512 + ks*64;
    float a0 = 0.f, a1 = 0.f, a2 = 0.f, a3 = 0.f;
    #pragma unroll 8
    for (int k = 0; k < 64; ++k){
        float w = wp[k*64];
        a0 += w * f0[k]; a1 += w * f1[k]; a2 += w * f2[k]; a3 += w * f3[k];
    }
    long base = (long)ks*(HIDDEN*KDIM) + (long)c0*KDIM + jd;
    MTp[base]         = a0;
    MTp[base + KDIM]  = a1;
    MTp[base + 2*KDIM]= a2;
    MTp[base + 3*KDIM]= a3;
}

// ---- 6a2. sum 8 partials, cast to bf16 ----
__global__ void k_prepM2(const float* __restrict__ MTp, ushort* __restrict__ MT){
    int i = blockIdx.x*256 + threadIdx.x;   // 0..98303
    if (i >= HIDDEN*KDIM) return;
    float s = 0.f;
    #pragma unroll
    for (int ks = 0; ks < 8; ++ks) s += MTp[(long)ks*(HIDDEN*KDIM) + i];
    MT[i] = f2bf(s);
}

// ---- 6b. folded bias: one block per channel, LDS reduce ----
__global__ __launch_bounds__(256) void k_bias(const float* __restrict__ b0,
                                              const float* __restrict__ b1,
                                              const float* __restrict__ b2,
                                              const float* __restrict__ fcW,
                                              const float* __restrict__ fcb,
                                              float* __restrict__ Bc){
    __shared__ float red[256];
    int c = blockIdx.x, t = threadIdx.x;
    const float* fw = fcW + (long)c*1536;
    float s = b0[t]*fw[t]          + b0[t+256]*fw[t+256]
            + b1[t]*fw[512+t]      + b1[t+256]*fw[512+t+256]
            + b2[t]*fw[1024+t]     + b2[t+256]*fw[1024+t+256];
    red[t] = s; __syncthreads();
    for (int off = 128; off > 0; off >>= 1){
        if (t < off) red[t] += red[t + off];
        __syncthreads();
    }
    if (t == 0) Bc[c] = fcb[c] + red[0];
}

// ---- 7. symmetric H^T H: node-major LDS, 78 upper-tri band pairs ----
// 4-wave blocks, (p&3)==w (20 acc max, VGPR ~128), NCH=2 chunks per block.
template<int W>
__device__ __forceinline__ void do_pairs(const short8* frag, float4v* acc){
    int p = 0, c = 0;
    #pragma unroll
    for (int i = 0; i < 12; ++i)
        #pragma unroll
        for (int j = i; j < 12; ++j){
            if ((p & 3) == W){
                acc[c] = __builtin_amdgcn_mfma_f32_16x16x32_bf16(frag[i], frag[j], acc[c], 0,0,0);
                ++c;
            }
            ++p;
        }
}
template<int W>
__device__ __forceinline__ void store_pairs(const float4v* acc, uint* Pb, int lane){
    int p = 0, c = 0;
    #pragma unroll
    for (int i = 0; i < 12; ++i)
        #pragma unroll
        for (int j = i; j < 12; ++j){
            if ((p & 3) == W){
                uint2v v;
                v[0] = (uint)f2bf(acc[c][0]) | ((uint)f2bf(acc[c][1]) << 16);
                v[1] = (uint)f2bf(acc[c][2]) | ((uint)f2bf(acc[c][3]) << 16);
                *(uint2v*)(Pb + p*128 + lane*2) = v;
                ++c;
            }
            ++p;
        }
}

__global__ __launch_bounds__(256, 2) void k_hth(const ushort* __restrict__ H,
                                                uint* __restrict__ P,
                                                float* __restrict__ msum){
    __shared__ ushort Ts[128*LDT];   // 49664 B, node-major
    int t = threadIdx.x;
    int w = t >> 6, lane = t & 63;
    int m16 = lane & 15, quad = lane >> 4;
    float4v acc[20] = {};
    #pragma unroll
    for (int cc = 0; cc < NCH; ++cc){
        int chunk = blockIdx.x * NCH + cc;
        int n0 = chunk * 128;
        #pragma unroll
        for (int it = 0; it < 12; ++it){
            int flat = it*256 + t;           // 128 rows * 24 segs
            int row = flat / 24, seg = flat - row*24;
            int gr = n0 + row;
            short8 v = {0,0,0,0,0,0,0,0};
            if (gr < N_NODES) v = *(const short8*)(H + (long)gr*KDIM + seg*8);
            *(short8*)(Ts + row*LDT + seg*8) = v;
        }
        __syncthreads();
        #pragma unroll
        for (int kt = 0; kt < 4; ++kt){
            short8 frag[12];
            #pragma unroll
            for (int b = 0; b < 12; ++b){
                short8 f;
                #pragma unroll
                for (int j = 0; j < 8; ++j)
                    f[j] = (short)Ts[(kt*32 + quad*8 + j)*LDT + b*16 + m16];
                frag[b] = f;
            }
            if      (w == 0) do_pairs<0>(frag, acc);
            else if (w == 1) do_pairs<1>(frag, acc);
            else if (w == 2) do_pairs<2>(frag, acc);
            else             do_pairs<3>(frag, acc);
        }
        // folded column sums (Ts untouched since staging)
        if (t < KDIM){
            float s = 0.f;
            #pragma unroll 4
            for (int n = 0; n < 128; ++n) s += bf2f(Ts[n*LDT + t]);
            atomicAdd(&msum[t], s);
        }
        __syncthreads();
    }
    uint* Pb = P + (long)blockIdx.x * PPB;
    if      (w == 0) store_pairs<0>(acc, Pb, lane);
    else if (w == 1) store_pairs<1>(acc, Pb, lane);
    else if (w == 2) store_pairs<2>(acc, Pb, lane);
    else             store_pairs<3>(acc, Pb, lane);
}

// ---- 8. split-K reduce of partials (coalesced) ----
__global__ void k_reduce(const uint* __restrict__ P, float* __restrict__ SP){
    int p = blockIdx.x * 256 + threadIdx.x;   // 0..9983
    int y = blockIdx.y;
    int b0 = y * 49, b1 = min(b0 + 49, NPART);
    float lo = 0.f, hi = 0.f;
    for (int b = b0; b < b1; ++b){
        uint v = P[(long)b*PPB + p];
        lo += bf2f((ushort)(v & 0xffff));
        hi += bf2f((ushort)(v >> 16));
    }
    float2v o; o[0] = lo; o[1] = hi;
    *(float2v*)(SP + (long)y*(NPAIR*256) + p*2) = o;
}

// ---- 9. finalize covariance C (both triangles) from fragment layout ----
__global__ void k_finC(const float* __restrict__ SP, const float* __restrict__ msum,
                       float* __restrict__ C){
    int idx = blockIdx.x * 256 + threadIdx.x;   // 0..19967
    float s = 0.f;
    #pragma unroll
    for (int y = 0; y < NSPLIT; ++y) s += SP[(long)y*(NPAIR*256) + idx];
    int h = idx & 1, pu = idx >> 1;
    int p = pu >> 7, rem = pu & 127;
    int l = rem >> 1, u = rem & 1;
    int r = u*2 + h;
    int pi = 0, pj = 0, off = 0;
    #pragma unroll
    for (int k = 0; k < 12; ++k){
        int len = 12 - k;
        if (p >= off && p < off + len){ pi = k; pj = k + (p - off); }
        off += len;
    }
    int m = pi*16 + (l >> 4)*4 + r;
    int n = pj*16 + (l & 15);
    const float invN = 1.f / (float)N_NODES;
    float v = s*invN - (msum[m]*invN)*(msum[n]*invN);
    C[m*KDIM + n] = v;
    C[n*KDIM + m] = v;
}

// ---- 10. Vp[ks][c][d] = partial C @ M_c over K-slice ks (split-K x4, 4c/block) ----
__global__ __launch_bounds__(192) void k_cv1(const float* __restrict__ C,
                                             const ushort* __restrict__ MT,
                                             float* __restrict__ Vp){
    int ks = blockIdx.x;          // 0..3, 48-wide K slice
    int c0 = blockIdx.y * 4;      // 0..508
    int d  = threadIdx.x;         // 0..191
    const ushort* m0 = MT + (long)(c0+0)*KDIM + ks*48;
    const ushort* m1 = MT + (long)(c0+1)*KDIM + ks*48;
    const ushort* m2 = MT + (long)(c0+2)*KDIM + ks*48;
    const ushort* m3 = MT + (long)(c0+3)*KDIM + ks*48;
    const float* cp = C + (long)(ks*48)*KDIM + d;
    float a0 = 0.f, a1 = 0.f, a2 = 0.f, a3 = 0.f;
    #pragma unroll 8
    for (int k = 0; k < 48; ++k){
        float cv = cp[(long)k*KDIM];
        a0 += bf2f(m0[k]) * cv; a1 += bf2f(m1[k]) * cv;
        a2 += bf2f(m2[k]) * cv; a3 += bf2f(m3[k]) * cv;
    }
    long base = (long)ks*(HIDDEN*KDIM) + (long)c0*KDIM + d;
    Vp[base]          = a0;
    Vp[base + KDIM]   = a1;
    Vp[base + 2*KDIM] = a2;
    Vp[base + 3*KDIM] = a3;
}

// ---- 11a. BN solve per channel: rr[c], tmpBN[c] (512 blocks, LDS reduce) ----
__global__ __launch_bounds__(192) void k_solveA(const float* __restrict__ Vp,
                                                const ushort* __restrict__ MT,
                                                const float* __restrict__ msum,
                                                const float* __restrict__ Bc,
                                                const float* __restrict__ gamma,
                                                const float* __restrict__ beta,
                                                float* __restrict__ rr,
                                                float* __restrict__ tmpBN){
    __shared__ float redM[192];
    __shared__ float redV[192];
    int c = blockIdx.x, d = threadIdx.x;
    const float invN = 1.f / (float)N_NODES;
    float m = bf2f(MT[(long)c*KDIM + d]);
    long vi = (long)c*KDIM + d;
    float vsum = Vp[vi] + Vp[vi + HIDDEN*KDIM] + Vp[vi + 2*HIDDEN*KDIM]
               + Vp[vi + 3*HIDDEN*KDIM];
    redM[d] = msum[d]*invN * m;
    redV[d] = vsum * m;
    __syncthreads();
    for (int off = 96; off >= 3; off >>= 1){
        if (d < off){ redM[d] += redM[d + off]; redV[d] += redV[d + off]; }
        __syncthreads();
    }
    if (d == 0){
        float mu  = Bc[c] + redM[0] + redM[1] + redM[2];
        float var = redV[0] + redV[1] + redV[2];
        float r = gamma[c] * rsqrtf(var + 1e-5f);
        rr[c] = r;
        tmpBN[c] = r * (Bc[c] - mu) + beta[c];
    }
}

// ---- 12. fold rho into M (+ block 0 computes cvec) ----
__global__ void k_buildG(const ushort* __restrict__ MT, const float* __restrict__ rr,
                         const float* __restrict__ q, const float* __restrict__ tmpBN,
                         ushort* __restrict__ GT, float* __restrict__ cvec){
    int o = blockIdx.x, d = threadIdx.x;  // 64 x 192
    float s = 0.f;
    #pragma unroll
    for (int k = 0; k < 8; ++k)
        s += q[k] * rr[k*64 + o] * bf2f(MT[(k*64 + o)*KDIM + d]);
    GT[o*KDIM + d] = f2bf(s);
    if (o == 0 && d < 64){
        float cs = 0.f;
        #pragma unroll
        for (int k = 0; k < 8; ++k) cs += q[k] * tmpBN[k*64 + d];
        cvec[d] = cs;
    }
}

// ---- 13. out = H @ GT^T + cvec ----
#define LDA 200
__global__ __launch_bounds__(256) void k_outgemm(const ushort* __restrict__ H,
                                                 const ushort* __restrict__ GT,
                                                 const float* __restrict__ cvec,
                                                 float* __restrict__ out){
    __shared__ ushort As[128*LDA];
    __shared__ ushort Gs[64*LDA];
    int t = threadIdx.x;
    int n0 = blockIdx.x * 128;
    int w = t >> 6, lane = t & 63;
    int m16 = lane & 15, quad = lane >> 4;
    int wr = w * 32;
    float4v acc[2][4] = {};
    #pragma unroll
    for (int it = 0; it < 12; ++it){
        int flat = it*256 + t;               // 128 rows * 24 segs
        int row = flat / 24, seg = flat - row*24;
        int gr = n0 + row;
        short8 v = {0,0,0,0,0,0,0,0};
        if (gr < N_NODES) v = *(const short8*)(H + (long)gr*KDIM + seg*8);
        *(short8*)(As + row*LDA + seg*8) = v;
    }
    #pragma unroll
    for (int it = 0; it < 6; ++it){
        int flat = it*256 + t;               // 64 rows * 24 segs
        int row = flat / 24, seg = flat - row*24;
        short8 v = *(const short8*)(GT + row*KDIM + seg*8);
        *(short8*)(Gs + row*LDA + seg*8) = v;
    }
    __syncthreads();
    #pragma unroll
    for (int kk = 0; kk < 192; kk += 32){
        short8 af[2], bf[4];
        #pragma unroll
        for (int i = 0; i < 2; ++i)
            af[i] = *(const short8*)(As + (wr + i*16 + m16)*LDA + kk + quad*8);
        #pragma unroll
        for (int j = 0; j < 4; ++j)
            bf[j] = *(const short8*)(Gs + (j*16 + m16)*LDA + kk + quad*8);
        #pragma unroll
        for (int i = 0; i < 2; ++i)
            #pragma unroll
            for (int j = 0; j < 4; ++j)
                acc[i][j] = __builtin_amdgcn_mfma_f32_16x16x32_bf16(af[i], bf[j], acc[i][j], 0,0,0);
    }
    #pragma unroll
    for (int i = 0; i < 2; ++i)
        #pragma unroll
        for (int j = 0; j < 4; ++j)
            #pragma unroll
            for (int r = 0; r < 4; ++r){
                int rowg = n0 + wr + i*16 + quad*4 + r;
                int o = j*16 + m16;
                if (rowg < N_NODES) out[(long)rowg*64 + o] = acc[i][j][r] + cvec[o];
            }
}

extern "C" void kernel_launch(void* const* d_in, const int* in_sizes, int n_in,
                              void* d_out, int out_size, void* d_ws, size_t ws_size,
                              hipStream_t stream) {
    const float* feats = (const float*)d_in[0];
    const int*   src   = (const int*)  d_in[1];
    const int*   dst   = (const int*)  d_in[2];
    const float* W0    = (const float*)d_in[3];
    const float* b0    = (const float*)d_in[4];
    const float* W1    = (const float*)d_in[5];
    const float* b1    = (const float*)d_in[6];
    const float* W2    = (const float*)d_in[7];
    const float* b2    = (const float*)d_in[8];
    const float* fcW   = (const float*)d_in[9];
    const float* fcb   = (const float*)d_in[10];
    const float* gamma = (const float*)d_in[11];
    const float* beta  = (const float*)d_in[12];
    const float* q     = (const float*)d_in[13];
    float* out = (float*)d_out;

    char* ws = (char*)d_ws;
    size_t off = 0;
    auto alloc = [&](size_t bytes) -> char* {
        char* p = ws + off;
        off = (off + bytes + 511) & ~(size_t)511;
        return p;
    };
    uint*   histA   = (uint*)  alloc((size_t)NB * NSLICE * 4);
    uint*   sbase   = (uint*)  alloc((size_t)NB * NSLICE * 4);
    uint*   btot    = (uint*)  alloc((size_t)NB * 4);
    uint*   bstart  = (uint*)  alloc((size_t)NB * 4);
    uint*   rec     = (uint*)  alloc((size_t)N_EDGES * 4);
    int*    deg     = (int*)   alloc((size_t)N_NODES * 4);
    int*    rowptr  = (int*)   alloc((size_t)N_NODES * 4);
    float*  nrm     = (float*) alloc((size_t)N_NODES * 4);
    int*    csr     = (int*)   alloc((size_t)N_EDGES * 4);
    ushort* Hx      = (ushort*)alloc((size_t)N_NODES * 64 * 2);
    ushort* HsB     = (ushort*)alloc((size_t)N_NODES * 64 * 2);
    ushort* H       = (ushort*)alloc((size_t)N_NODES * KDIM * 2);
    ushort* MT      = (ushort*)alloc((size_t)HIDDEN * KDIM * 2);
    float*  MTp     = (float*) alloc((size_t)8 * HIDDEN * KDIM * 4);
    float*  Bc      = (float*) alloc((size_t)HIDDEN * 4);
    float*  msum    = (float*) alloc((size_t)KDIM * 4);
    uint*   P       = (uint*)  alloc((size_t)NPART * PPB * 4);
    float*  SP      = (float*) alloc((size_t)NSPLIT * NPAIR * 256 * 4);
    float*  C       = (float*) alloc((size_t)SDIM * 4);
    float*  Vp      = (float*) alloc((size_t)4 * HIDDEN * KDIM * 4);
    float*  rr      = (float*) alloc((size_t)HIDDEN * 4);
    float*  tmpBN   = (float*) alloc((size_t)HIDDEN * 4);
    float*  cvec    = (float*) alloc((size_t)64 * 4);
    ushort* GT      = (ushort*)alloc((size_t)64 * KDIM * 2);
    (void)ws_size; (void)n_in; (void)in_sizes; (void)out_size;

    hipMemsetAsync(msum, 0, (size_t)KDIM * 4, stream);

    k_histA <<<NSLICE, 1024, 0, stream>>>(dst, histA);
    k_scanSl<<<NB, 256, 0, stream>>>(histA, sbase, btot);
    k_scanBk<<<1, 512, 0, stream>>>(btot, bstart);
    k_packA <<<NSLICE, 1024, 0, stream>>>(src, dst, sbase, bstart, rec);
    k_passB <<<NB, 256, 0, stream>>>(rec, bstart, btot, feats, csr, deg, rowptr, nrm, Hx);

    int aggGrid = (N_NODES + 7) / 8;
    k_agg<true> <<<aggGrid, 256, 0, stream>>>(Hx,  H, 0,   HsB, rowptr, deg, nrm, csr);
    k_agg<true> <<<aggGrid, 256, 0, stream>>>(HsB, H, 64,  Hx,  rowptr, deg, nrm, csr);
    k_agg<false><<<aggGrid, 256, 0, stream>>>(Hx,  H, 128, HsB, rowptr, deg, nrm, csr);

    dim3 pmGrid(8, HIDDEN/4);
    k_prepM1<<<pmGrid, 192, 0, stream>>>(W0, W1, W2, fcW, MTp);
    k_prepM2<<<(HIDDEN*KDIM + 255)/256, 256, 0, stream>>>(MTp, MT);
    k_bias <<<HIDDEN, 256, 0, stream>>>(b0, b1, b2, fcW, fcb, Bc);

    k_hth   <<<NPART, 256, 0, stream>>>(H, P, msum);
    dim3 rGrid(PPB/256, NSPLIT);
    k_reduce<<<rGrid, 256, 0, stream>>>(P, SP);
    k_finC  <<<NPAIR, 256, 0, stream>>>(SP, msum, C);
    dim3 cvGrid(4, HIDDEN/4);
    k_cv1   <<<cvGrid, 192, 0, stream>>>(C, MT, Vp);
    k_solveA<<<HIDDEN, 192, 0, stream>>>(Vp, MT, msum, Bc, gamma, beta, rr, tmpBN);
    k_buildG<<<64, KDIM, 0, stream>>>(MT, rr, q, tmpBN, GT, cvec);

    k_outgemm<<<NCHUNK, 256, 0, stream>>>(H, GT, cvec, out);
}